// Round 10
// baseline (2956.814 us; speedup 1.0000x reference)
//
#include <hip/hip_runtime.h>
#include <math.h>

#define BATCH   64
#define SEQLEN  128
#define EMBED   512
#define HID     1024
#define NSTEP   127
#define OUT0    65
#define NOUT    62
#define NBLK    512
#define NTHR    512

// LDS layout (floats):
//   wlds [uu 2][k 1536][gate 4] = 12288 @ 0        (48 KB, persistent)
//   red  phaseA 2048 @ 12288, phaseB 1024 @ 14336, phaseC 512 @ 15360
//   c    128 @ 15872   (c-state: [uu][b])
//   head 128 @ 16000   (h*w_ans handoff: [uu][b])
#define REDA_OFF 12288
#define REDB_OFF 14336
#define REDC_OFF 15360
#define C_OFF    15872
#define HEAD_OFF 16000
#define LDS_FLOATS 16128   // 64512 B; 2 blocks/CU = 129 KB < 160 KB

__device__ __forceinline__ float sigmoidf_(float x) { return 1.f / (1.f + expf(-x)); }

// 16 FMAs: 4 gates (wv components) x 4 batches (xv components)
#define FMA16(WV, XV)                                                   \
    acc[0][0] = fmaf(WV.x, XV.x, acc[0][0]);                            \
    acc[0][1] = fmaf(WV.x, XV.y, acc[0][1]);                            \
    acc[0][2] = fmaf(WV.x, XV.z, acc[0][2]);                            \
    acc[0][3] = fmaf(WV.x, XV.w, acc[0][3]);                            \
    acc[1][0] = fmaf(WV.y, XV.x, acc[1][0]);                            \
    acc[1][1] = fmaf(WV.y, XV.y, acc[1][1]);                            \
    acc[1][2] = fmaf(WV.y, XV.z, acc[1][2]);                            \
    acc[1][3] = fmaf(WV.y, XV.w, acc[1][3]);                            \
    acc[2][0] = fmaf(WV.z, XV.x, acc[2][0]);                            \
    acc[2][1] = fmaf(WV.z, XV.y, acc[2][1]);                            \
    acc[2][2] = fmaf(WV.z, XV.z, acc[2][2]);                            \
    acc[2][3] = fmaf(WV.z, XV.w, acc[2][3]);                            \
    acc[3][0] = fmaf(WV.w, XV.x, acc[3][0]);                            \
    acc[3][1] = fmaf(WV.w, XV.y, acc[3][1]);                            \
    acc[3][2] = fmaf(WV.w, XV.z, acc[3][2]);                            \
    acc[3][3] = fmaf(WV.w, XV.w, acc[3][3]);

// Transpose h0/c0 ([b][u]) into [u][b] working layout.
__global__ __launch_bounds__(256) void init_state(
    const float* __restrict__ h0, const float* __restrict__ c0,
    float* __restrict__ hT, float* __restrict__ cT)
{
    int id = blockIdx.x * 256 + threadIdx.x;   // u*64+b
    int u = id >> 6, b = id & 63;
    hT[id] = h0[b * HID + u];
    cT[id] = c0[b * HID + u];
}

// Build xT[t][k][b] = embed[prob[b][t]][k] (one-time gather+transpose).
__global__ __launch_bounds__(256) void embed_transpose(
    const int* __restrict__ prob, const float* __restrict__ embed,
    float* __restrict__ xT)
{
    __shared__ float xe[64 * 132];
    int t = blockIdx.x;
    int tid = threadIdx.x;
    for (int kt = 0; kt < 4; ++kt) {
        #pragma unroll
        for (int i = 0; i < 8; ++i) {
            int id = tid + i * 256;
            int b  = id >> 5;
            int k4 = id & 31;
            int tok = prob[b * SEQLEN + t];
            float4 v = *(const float4*)(embed + (size_t)tok * EMBED + kt * 128 + k4 * 4);
            *(float4*)(&xe[b * 132 + k4 * 4]) = v;
        }
        __syncthreads();
        #pragma unroll
        for (int i = 0; i < 8; ++i) {
            int id = tid + i * 256;
            int kl = id >> 4;
            int b4 = id & 15;
            float4 v;
            v.x = xe[(b4 * 4 + 0) * 132 + kl];
            v.y = xe[(b4 * 4 + 1) * 132 + kl];
            v.z = xe[(b4 * 4 + 2) * 132 + kl];
            v.w = xe[(b4 * 4 + 3) * 132 + kl];
            *(float4*)(&xT[((size_t)t * EMBED + kt * 128 + kl) * 64 + b4 * 4]) = v;
        }
        __syncthreads();
    }
}

// ===================== persistent path, lane-split weights =====================
// Round-10 change: lane = (bq 0..15, uu 0..1, kp 0..1). Per 2-k group a thread
// issues ONE ds_read_b128 (its unit's 4 gate-weights at k=kg+kp; 4 distinct
// 16B chunks per wave instr, conflict-free) + ONE coalesced global b128 x/h
// read (4 batches) + 16 FMA. DS-pipe instrs drop 4x (384 -> 96 per thread per
// step) -- round 9's measured wall was the per-CU LDS return path at
// ~49k cyc/step. kp-pairs reduced with one shfl_xor(1) butterfly; ksl tree
// keeps the same LDS image with b128 accesses. Dataflow sync unchanged.
__global__ __launch_bounds__(NTHR, 4) void lstm_persist_hist(
    const float* __restrict__ xT, float* __restrict__ h_hist,
    const float* __restrict__ cT,
    const float* __restrict__ w_ih, const float* __restrict__ w_hh,
    const float* __restrict__ b_ih, const float* __restrict__ b_hh,
    const float* __restrict__ w_ans, float* __restrict__ pout,
    int* __restrict__ bar)
{
    __shared__ float lds[LDS_FLOATS];
    const int tid  = threadIdx.x;
    const int bid  = blockIdx.x;
    const int lane = tid & 63;
    const int ksl  = __builtin_amdgcn_readfirstlane(tid >> 6);  // 0..7
    const int kp   = lane & 1;            // k parity within 2-k group
    const int uu   = (lane >> 1) & 1;     // unit
    const int bq   = lane >> 2;           // batch quad 0..15
    const int u0   = bid * 2;

    int* sliceCnt = bar + (bid >> 6) * 32;
    int* mySlice  = bar + 256 + (bid >> 6) * 32;
    int* waitGo   = bar + 256 + ksl * 32;

    // one-time: weights -> LDS  [uu][k][gate]
    for (int idx = tid; idx < 12288; idx += NTHR) {
        int r  = idx / 1536;
        int k  = idx - r * 1536;
        int u2 = r & 1, gate = r >> 1;
        int row = gate * HID + u0 + u2;
        float v = (k < EMBED) ? w_ih[(size_t)row * EMBED + k]
                              : w_hh[(size_t)row * HID + (k - EMBED)];
        lds[(u2 * 1536 + k) * 4 + gate] = v;
    }
    if (tid < 128) lds[C_OFF + tid] = cT[u0 * 64 + tid];

    // per-lane bias / w_ans for THIS lane's unit
    float bs[4], wansu;
    #pragma unroll
    for (int j = 0; j < 4; ++j)
        bs[j] = b_ih[j * HID + u0 + uu] + b_hh[j * HID + u0 + uu];
    wansu = w_ans[u0 + uu];
    const int wbase = uu * 6144;          // float offset of my unit's weight plane
    __syncthreads();

    for (int t = 0; t < NSTEP; ++t) {
        const float* xt = xT + (size_t)t * EMBED * 64;
        const float* ht = h_hist + (size_t)t * HID * 64;
        float* hn_buf   = h_hist + (size_t)(t + 1) * HID * 64;

        float acc[4][4];
        #pragma unroll
        for (int j = 0; j < 4; ++j)
            #pragma unroll
            for (int i = 0; i < 4; ++i) acc[j][i] = 0.f;

        // ---- x phase: 32 2-k groups (independent of h(t-1)) ----
        const int kx0 = ksl * 64;
        #pragma unroll 4
        for (int g = 0; g < 32; ++g) {
            const int k = kx0 + 2 * g + kp;
            float4 wv = *(const float4*)&lds[wbase + k * 4];
            float4 xv = *(const float4*)(xt + (size_t)k * 64 + bq * 4);
            FMA16(wv, xv)
        }

        // ---- per-wave wait: only THIS wave's h-slice must be ready ----
        if (t > 0) {
            while (__hip_atomic_load(waitGo, __ATOMIC_RELAXED,
                                     __HIP_MEMORY_SCOPE_AGENT) < t)
                __builtin_amdgcn_s_sleep(4);
            __builtin_amdgcn_fence(__ATOMIC_ACQUIRE, "workgroup"); // no cache inv
        }

        // ---- h phase: 64 2-k groups ----
        const int kh0 = ksl * 128;
        #pragma unroll 4
        for (int g = 0; g < 64; ++g) {
            const int kh = kh0 + 2 * g + kp;
            float4 wv = *(const float4*)&lds[wbase + (EMBED + kh) * 4];
            float4 xv = *(const float4*)(ht + (size_t)kh * 64 + bq * 4);
            FMA16(wv, xv)
        }

        // ---- kp butterfly: both kp lanes end with the pair sum ----
        #pragma unroll
        for (int j = 0; j < 4; ++j)
            #pragma unroll
            for (int i = 0; i < 4; ++i)
                acc[j][i] += __shfl_xor(acc[j][i], 1, 64);

        // ---- ksl tree 8 -> 4 -> 2 -> 1 (b128, kp0 lanes store) ----
        if (ksl >= 4 && kp == 0) {
            #pragma unroll
            for (int j = 0; j < 4; ++j) {
                float4 v = { acc[j][0], acc[j][1], acc[j][2], acc[j][3] };
                *(float4*)&lds[REDA_OFF + (((ksl - 4) * 8) + uu * 4 + j) * 64 + bq * 4] = v;
            }
        }
        __syncthreads();
        if (ksl < 4) {
            #pragma unroll
            for (int j = 0; j < 4; ++j) {
                float4 v = *(const float4*)&lds[REDA_OFF + ((ksl * 8) + uu * 4 + j) * 64 + bq * 4];
                acc[j][0] += v.x; acc[j][1] += v.y; acc[j][2] += v.z; acc[j][3] += v.w;
            }
        }
        if ((ksl == 2 || ksl == 3) && kp == 0) {
            #pragma unroll
            for (int j = 0; j < 4; ++j) {
                float4 v = { acc[j][0], acc[j][1], acc[j][2], acc[j][3] };
                *(float4*)&lds[REDB_OFF + (((ksl - 2) * 8) + uu * 4 + j) * 64 + bq * 4] = v;
            }
        }
        __syncthreads();
        if (ksl < 2) {
            #pragma unroll
            for (int j = 0; j < 4; ++j) {
                float4 v = *(const float4*)&lds[REDB_OFF + ((ksl * 8) + uu * 4 + j) * 64 + bq * 4];
                acc[j][0] += v.x; acc[j][1] += v.y; acc[j][2] += v.z; acc[j][3] += v.w;
            }
        }
        if (ksl == 1 && kp == 0) {
            #pragma unroll
            for (int j = 0; j < 4; ++j) {
                float4 v = { acc[j][0], acc[j][1], acc[j][2], acc[j][3] };
                *(float4*)&lds[REDC_OFF + (uu * 4 + j) * 64 + bq * 4] = v;
            }
        }
        __syncthreads();
        if (ksl == 0) {
            #pragma unroll
            for (int j = 0; j < 4; ++j) {
                float4 v = *(const float4*)&lds[REDC_OFF + (uu * 4 + j) * 64 + bq * 4];
                acc[j][0] += v.x; acc[j][1] += v.y; acc[j][2] += v.z; acc[j][3] += v.w;
            }
            // finalize: lane covers (uu, batches bq*4..+3); kp pair splits stores
            #pragma unroll
            for (int i = 0; i < 4; ++i) {
                float i_g = sigmoidf_(acc[0][i] + bs[0]);
                float f_g = sigmoidf_(acc[1][i] + bs[1]);
                float g_g = tanhf   (acc[2][i] + bs[2]);
                float o_g = sigmoidf_(acc[3][i] + bs[3]);
                int b2 = bq * 4 + i;
                float c_old = lds[C_OFF + uu * 64 + b2];
                float c_new = f_g * c_old + i_g * g_g;
                float h_new = o_g * tanhf(c_new);
                if ((i >> 1) == kp) {   // each kp lane stores its 2 batches
                    lds[C_OFF + uu * 64 + b2] = c_new;
                    __hip_atomic_store(&hn_buf[(u0 + uu) * 64 + b2], h_new,
                                       __ATOMIC_RELAXED, __HIP_MEMORY_SCOPE_AGENT);
                    lds[HEAD_OFF + uu * 64 + b2] = h_new * wansu;
                }
            }
        }

        __syncthreads();   // drains wave-0 h-stores (vmcnt 0) before arrive
        if (t >= OUT0 && tid < 64) {
            pout[((size_t)(t - OUT0) * NBLK + bid) * 64 + tid] =
                lds[HEAD_OFF + tid] + lds[HEAD_OFF + 64 + tid];
        }
        if (t == NSTEP - 1) break;
        if (tid == 0) {
            int r = __hip_atomic_fetch_add(sliceCnt, 1, __ATOMIC_RELAXED,
                                           __HIP_MEMORY_SCOPE_AGENT);
            if (r == 64 * (t + 1) - 1)
                __hip_atomic_store(mySlice, t + 1, __ATOMIC_RELAXED,
                                   __HIP_MEMORY_SCOPE_AGENT);
        }
    }
}

// out[b][col] = sum over 512 block partials + bias.
__global__ __launch_bounds__(256) void finalize_persist(
    const float* __restrict__ pout, const float* __restrict__ b_ans,
    float* __restrict__ out)
{
    __shared__ float r[256];
    int col = blockIdx.x;
    int tid = threadIdx.x;
    int b = tid & 63, q = tid >> 6;
    float s = 0.f;
    for (int i = q; i < NBLK; i += 4)
        s += pout[((size_t)col * NBLK + i) * 64 + b];
    r[tid] = s;
    __syncthreads();
    if (tid < 64)
        out[tid * NOUT + col] = r[tid] + r[64 + tid] + r[128 + tid] + r[192 + tid]
                              + b_ans[0];
}

// ===================== per-step fallback (round-3 proven) =====================
#define F_HEADOFF 4096
__global__ __launch_bounds__(1024, 4) void lstm_step_fb(
    const float* __restrict__ xT, const float* __restrict__ hT_in,
    float* __restrict__ hT_out, float* __restrict__ cT,
    const float* __restrict__ w_ih, const float* __restrict__ w_hh,
    const float* __restrict__ b_ih, const float* __restrict__ b_hh,
    const float* __restrict__ w_ans, float* __restrict__ pout, int t)
{
    __shared__ float lds[F_HEADOFF + 256];
    const int tid = threadIdx.x;
    const int bid = blockIdx.x;
    const int b   = tid & 63;
    const int ws  = __builtin_amdgcn_readfirstlane(tid >> 6);
    const int uu  = ws & 3;
    const int ksl = ws >> 2;
    const int u   = bid * 4 + uu;

    const float* wr_i[4];
    const float* wr_h[4];
    #pragma unroll
    for (int j = 0; j < 4; ++j) {
        wr_i[j] = w_ih + (size_t)(j * HID + u) * EMBED;
        wr_h[j] = w_hh + (size_t)(j * HID + u) * HID;
    }
    float acc[4];
    acc[0] = acc[1] = acc[2] = acc[3] = 0.f;
    {
        const float* xt = xT + (size_t)t * EMBED * 64;
        const int k0 = ksl * 128;
        #pragma unroll 4
        for (int g = 0; g < 32; ++g) {
            const int k = k0 + g * 4;
            float4 wv0 = *(const float4*)(wr_i[0] + k);
            float4 wv1 = *(const float4*)(wr_i[1] + k);
            float4 wv2 = *(const float4*)(wr_i[2] + k);
            float4 wv3 = *(const float4*)(wr_i[3] + k);
            float x0 = xt[(k + 0) * 64 + b];
            float x1 = xt[(k + 1) * 64 + b];
            float x2 = xt[(k + 2) * 64 + b];
            float x3 = xt[(k + 3) * 64 + b];
            acc[0] = fmaf(wv0.x, x0, acc[0]); acc[0] = fmaf(wv0.y, x1, acc[0]);
            acc[0] = fmaf(wv0.z, x2, acc[0]); acc[0] = fmaf(wv0.w, x3, acc[0]);
            acc[1] = fmaf(wv1.x, x0, acc[1]); acc[1] = fmaf(wv1.y, x1, acc[1]);
            acc[1] = fmaf(wv1.z, x2, acc[1]); acc[1] = fmaf(wv1.w, x3, acc[1]);
            acc[2] = fmaf(wv2.x, x0, acc[2]); acc[2] = fmaf(wv2.y, x1, acc[2]);
            acc[2] = fmaf(wv2.z, x2, acc[2]); acc[2] = fmaf(wv2.w, x3, acc[2]);
            acc[3] = fmaf(wv3.x, x0, acc[3]); acc[3] = fmaf(wv3.y, x1, acc[3]);
            acc[3] = fmaf(wv3.z, x2, acc[3]); acc[3] = fmaf(wv3.w, x3, acc[3]);
        }
    }
    {
        const int k0 = ksl * 256;
        #pragma unroll 4
        for (int g = 0; g < 64; ++g) {
            const int k = k0 + g * 4;
            float4 wv0 = *(const float4*)(wr_h[0] + k);
            float4 wv1 = *(const float4*)(wr_h[1] + k);
            float4 wv2 = *(const float4*)(wr_h[2] + k);
            float4 wv3 = *(const float4*)(wr_h[3] + k);
            float x0 = hT_in[(k + 0) * 64 + b];
            float x1 = hT_in[(k + 1) * 64 + b];
            float x2 = hT_in[(k + 2) * 64 + b];
            float x3 = hT_in[(k + 3) * 64 + b];
            acc[0] = fmaf(wv0.x, x0, acc[0]); acc[0] = fmaf(wv0.y, x1, acc[0]);
            acc[0] = fmaf(wv0.z, x2, acc[0]); acc[0] = fmaf(wv0.w, x3, acc[0]);
            acc[1] = fmaf(wv1.x, x0, acc[1]); acc[1] = fmaf(wv1.y, x1, acc[1]);
            acc[1] = fmaf(wv1.z, x2, acc[1]); acc[1] = fmaf(wv1.w, x3, acc[1]);
            acc[2] = fmaf(wv2.x, x0, acc[2]); acc[2] = fmaf(wv2.y, x1, acc[2]);
            acc[2] = fmaf(wv2.z, x2, acc[2]); acc[2] = fmaf(wv2.w, x3, acc[2]);
            acc[3] = fmaf(wv3.x, x0, acc[3]); acc[3] = fmaf(wv3.y, x1, acc[3]);
            acc[3] = fmaf(wv3.z, x2, acc[3]); acc[3] = fmaf(wv3.w, x3, acc[3]);
        }
    }
    #pragma unroll
    for (int j = 0; j < 4; ++j)
        lds[((ksl * 4 + uu) * 4 + j) * 64 + b] = acc[j];
    __syncthreads();
    if (tid < 256) {
        int b2  = tid & 63;
        int uu2 = tid >> 6;
        int u2  = bid * 4 + uu2;
        float s[4];
        #pragma unroll
        for (int j = 0; j < 4; ++j) {
            s[j] = lds[((0 * 4 + uu2) * 4 + j) * 64 + b2]
                 + lds[((1 * 4 + uu2) * 4 + j) * 64 + b2]
                 + lds[((2 * 4 + uu2) * 4 + j) * 64 + b2]
                 + lds[((3 * 4 + uu2) * 4 + j) * 64 + b2];
            int rj = j * HID + u2;
            s[j] += b_ih[rj] + b_hh[rj];
        }
        float ig = sigmoidf_(s[0]);
        float fg = sigmoidf_(s[1]);
        float gg = tanhf(s[2]);
        float og = sigmoidf_(s[3]);
        float cn = fg * cT[u2 * 64 + b2] + ig * gg;
        float hn = og * tanhf(cn);
        cT[u2 * 64 + b2]     = cn;
        hT_out[u2 * 64 + b2] = hn;
        lds[F_HEADOFF + uu2 * 64 + b2] = hn * w_ans[u2];
    }
    __syncthreads();
    if (t >= OUT0 && tid < 64) {
        float sum = lds[F_HEADOFF + tid]       + lds[F_HEADOFF + 64 + tid]
                  + lds[F_HEADOFF + 128 + tid] + lds[F_HEADOFF + 192 + tid];
        pout[((size_t)((t - OUT0) * 64 + tid)) * 256 + bid] = sum;
    }
}

__global__ __launch_bounds__(64) void finalize_fb(
    const float* __restrict__ pout, const float* __restrict__ b_ans,
    float* __restrict__ out)
{
    int blk  = blockIdx.x;
    int col  = blk >> 6;
    int bb   = blk & 63;
    int lane = threadIdx.x;
    const float* p = pout + (size_t)(col * 64 + bb) * 256;
    float s = p[lane] + p[lane + 64] + p[lane + 128] + p[lane + 192];
    #pragma unroll
    for (int off = 32; off > 0; off >>= 1) s += __shfl_down(s, off);
    if (lane == 0) out[bb * NOUT + col] = s + b_ans[0];
}

extern "C" void kernel_launch(void* const* d_in, const int* in_sizes, int n_in,
                              void* d_out, int out_size, void* d_ws, size_t ws_size,
                              hipStream_t stream)
{
    const int*   prob  = (const int*)  d_in[0];
    const float* embed = (const float*)d_in[2];
    const float* w_ih  = (const float*)d_in[3];
    const float* w_hh  = (const float*)d_in[4];
    const float* b_ih  = (const float*)d_in[5];
    const float* b_hh  = (const float*)d_in[6];
    const float* w_ans = (const float*)d_in[7];
    const float* b_ans = (const float*)d_in[8];
    const float* h0    = (const float*)d_in[9];
    const float* c0    = (const float*)d_in[10];

    float* ws = (float*)d_ws;

    float* cT     = ws;                    // 65,536
    float* pout   = ws + 65536;            // 2,031,616
    float* xT     = ws + 2097152;          // 4,161,536
    float* h_hist = ws + 6258688;          // 128*65,536 = 8,388,608
    int*   bar    = (int*)(ws + 14647296); // 512 ints

    hipMemsetAsync(bar, 0, 2048, stream);
    init_state<<<256, 256, 0, stream>>>(h0, c0, h_hist, cT);
    embed_transpose<<<NSTEP, 256, 0, stream>>>(prob, embed, xT);

    void* args[] = {
        (void*)&xT, (void*)&h_hist, (void*)&cT,
        (void*)&w_ih, (void*)&w_hh, (void*)&b_ih, (void*)&b_hh,
        (void*)&w_ans, (void*)&pout, (void*)&bar
    };
    hipError_t err = hipLaunchCooperativeKernel((const void*)lstm_persist_hist,
                                                dim3(NBLK), dim3(NTHR),
                                                args, 0, stream);
    if (err == hipSuccess) {
        finalize_persist<<<NOUT, 256, 0, stream>>>(pout, b_ans, (float*)d_out);
    } else {
        for (int t = 0; t < NSTEP; ++t) {
            float* hin  = h_hist + (size_t)(t & 1) * 65536;
            float* hout = h_hist + (size_t)((t + 1) & 1) * 65536;
            lstm_step_fb<<<256, 1024, 0, stream>>>(xT, hin, hout, cT, w_ih, w_hh,
                                                   b_ih, b_hh, w_ans, pout, t);
        }
        finalize_fb<<<NOUT * 64, 64, 0, stream>>>(pout, b_ans, (float*)d_out);
    }
}

// Round 11
// 1251.500 us; speedup vs baseline: 2.3626x; 2.3626x over previous
//
#include <hip/hip_runtime.h>
#include <math.h>

#define BATCH   64
#define SEQLEN  128
#define EMBED   512
#define HID     1024
#define NSTEP   127
#define OUT0    65
#define NOUT    62

typedef unsigned short ushort_t;
typedef __attribute__((ext_vector_type(8))) __bf16 bf16x8;
typedef __attribute__((ext_vector_type(4))) float  f32x4;

__device__ __forceinline__ float sigmoidf_(float x) { return 1.f / (1.f + expf(-x)); }

__device__ __forceinline__ ushort_t f2bf(float f) {
    unsigned u = __builtin_bit_cast(unsigned, f);
    unsigned r = (u + 0x7FFFu + ((u >> 16) & 1u)) >> 16;   // round-to-nearest-even
    return (ushort_t)r;
}
__device__ __forceinline__ float bf2f(ushort_t s) {
    unsigned u = ((unsigned)s) << 16;
    return __builtin_bit_cast(float, u);
}

// ===================== MFMA path prep =====================

// cT[u][b] from c0; hf[0] fragment image from h0 (split bf16 hi/lo).
__global__ __launch_bounds__(256) void init_mfma(
    const float* __restrict__ h0, const float* __restrict__ c0,
    float* __restrict__ cT, ushort_t* __restrict__ hf_hi, ushort_t* __restrict__ hf_lo)
{
    int id = blockIdx.x * 256 + threadIdx.x;   // u*64+b, 65536 total
    int u = id >> 6, b = id & 63;
    cT[id] = c0[b * HID + u];
    float h = h0[b * HID + u];
    ushort_t hs = f2bf(h);
    ushort_t ls = f2bf(h - bf2f(hs));
    size_t idx = (((size_t)(u >> 5)) * 4 + (b >> 4)) * 512
               + ((((u & 31) >> 3) * 16) + (b & 15)) * 8 + (u & 7);
    hf_hi[idx] = hs;
    hf_lo[idx] = ls;
}

// xf[t] fragment image: x = embed[prob[b][t]][k], split bf16 hi/lo.
__global__ __launch_bounds__(256) void embed_frag(
    const int* __restrict__ prob, const float* __restrict__ embed,
    ushort_t* __restrict__ xf_hi, ushort_t* __restrict__ xf_lo)
{
    int t = blockIdx.x;
    for (int e = threadIdx.x; e < 64 * 512; e += 256) {
        int k = e & 511, b = e >> 9;
        int tok = prob[b * SEQLEN + t];
        float f = embed[(size_t)tok * EMBED + k];
        ushort_t hs = f2bf(f);
        ushort_t ls = f2bf(f - bf2f(hs));
        size_t idx = (((size_t)t * 16 + (k >> 5)) * 4 + (b >> 4)) * 512
                   + ((((k & 31) >> 3) * 16) + (b & 15)) * 8 + (k & 7);
        xf_hi[idx] = hs;
        xf_lo[idx] = ls;
    }
}

// ===================== MFMA persistent kernel =====================
// 256 blocks x 256 thr (1 block/CU, 4 waves). Block = 4 units = 16 gate-rows
// (m = unit*4 + gate) = the MFMA M-tile. Wave w = N-tile (batches w*16..+15).
// K = 1536 = 48 ksteps of 32. bf16x3: D += Whi*Xhi + Wlo*Xhi + Whi*Xlo (fp32 acc).
// Weights pre-split into A-frag layout in 96KB dynamic LDS (lane L reads its
// 16B at off = ks*512 + L*8 -- all lanes distinct contiguous, conflict-free).
// D C-layout: lane(q=L>>4, n=L&15) holds gates 0..3 of (unit u0+q, batch w*16+n)
// -> nonlinearity in-lane, c-state in a register, no reduction tree.
// h split back to bf16 hi/lo, scattered to hf[t+1] frag image (fresh buffer per
// step -> plain cached consumer loads). Full 256-block striped barrier.
__global__ __launch_bounds__(256) void lstm_mfma(
    const ushort_t* __restrict__ xf_hi, const ushort_t* __restrict__ xf_lo,
    ushort_t* __restrict__ hf_hi, ushort_t* __restrict__ hf_lo,
    const float* __restrict__ cT,
    const float* __restrict__ w_ih, const float* __restrict__ w_hh,
    const float* __restrict__ b_ih, const float* __restrict__ b_hh,
    const float* __restrict__ w_ans, float* __restrict__ pout,
    int* __restrict__ bar)
{
    extern __shared__ ushort_t smem[];          // 49152 + 49152 ushorts
    ushort_t* a_hi = smem;                      // [ks 48][512]
    ushort_t* a_lo = smem + 48 * 512;

    const int tid = threadIdx.x;
    const int bid = blockIdx.x;
    const int w   = tid >> 6;        // wave = N-tile
    const int L   = tid & 63;
    const int n   = L & 15;
    const int q   = L >> 4;
    const int u0  = bid * 4;
    const int ug  = u0 + q;          // this lane's global unit
    const int bg  = w * 16 + n;      // this lane's global batch

    int* cnt  = bar + (bid & 7) * 32;
    int* scnt = bar + 256;
    int* go   = bar + 288;

    // ---- one-time: weight split -> A-frag LDS image ----
    for (int m = 0; m < 16; ++m) {
        int unit = m >> 2, gate = m & 3;
        size_t rowg = (size_t)gate * HID + u0 + unit;
        #pragma unroll
        for (int i = 0; i < 6; ++i) {
            int k = tid + i * 256;                 // 0..1535
            float f = (k < EMBED) ? w_ih[rowg * EMBED + k]
                                  : w_hh[rowg * HID + (k - EMBED)];
            ushort_t hs = f2bf(f);
            ushort_t ls = f2bf(f - bf2f(hs));
            int off = (k >> 5) * 512 + (((k & 31) >> 3) * 16 + m) * 8 + (k & 7);
            a_hi[off] = hs;
            a_lo[off] = ls;
        }
    }

    float c = cT[ug * 64 + bg];
    float bs[4];
    #pragma unroll
    for (int j = 0; j < 4; ++j) bs[j] = b_ih[j * HID + ug] + b_hh[j * HID + ug];
    const float wansu = w_ans[ug];
    __syncthreads();

    for (int t = 0; t < NSTEP; ++t) {
        f32x4 acc = {0.f, 0.f, 0.f, 0.f};

        // ---- x phase (independent of h(t-1)) : 16 ksteps x 3 MFMA ----
        {
            const ushort_t* xh = xf_hi + (((size_t)t * 16) * 4 + w) * 512 + L * 8;
            const ushort_t* xl = xf_lo + (((size_t)t * 16) * 4 + w) * 512 + L * 8;
            for (int ks = 0; ks < 16; ++ks) {
                bf16x8 ah = *(const bf16x8*)(a_hi + ks * 512 + L * 8);
                bf16x8 al = *(const bf16x8*)(a_lo + ks * 512 + L * 8);
                bf16x8 bh = *(const bf16x8*)(xh + (size_t)ks * 2048);
                bf16x8 bl = *(const bf16x8*)(xl + (size_t)ks * 2048);
                acc = __builtin_amdgcn_mfma_f32_16x16x32_bf16(ah, bh, acc, 0, 0, 0);
                acc = __builtin_amdgcn_mfma_f32_16x16x32_bf16(al, bh, acc, 0, 0, 0);
                acc = __builtin_amdgcn_mfma_f32_16x16x32_bf16(ah, bl, acc, 0, 0, 0);
            }
        }

        // ---- wait for h(t): read-only spin (no cache inv) ----
        if (t > 0) {
            while (__hip_atomic_load(go, __ATOMIC_RELAXED,
                                     __HIP_MEMORY_SCOPE_AGENT) < t)
                __builtin_amdgcn_s_sleep(2);
            __builtin_amdgcn_fence(__ATOMIC_ACQUIRE, "workgroup");
        }

        // ---- h phase: 32 ksteps x 3 MFMA ----
        {
            const ushort_t* hh = hf_hi + (((size_t)t * 32) * 4 + w) * 512 + L * 8;
            const ushort_t* hl = hf_lo + (((size_t)t * 32) * 4 + w) * 512 + L * 8;
            for (int ks = 0; ks < 32; ++ks) {
                bf16x8 ah = *(const bf16x8*)(a_hi + (16 + ks) * 512 + L * 8);
                bf16x8 al = *(const bf16x8*)(a_lo + (16 + ks) * 512 + L * 8);
                bf16x8 bh = *(const bf16x8*)(hh + (size_t)ks * 2048);
                bf16x8 bl = *(const bf16x8*)(hl + (size_t)ks * 2048);
                acc = __builtin_amdgcn_mfma_f32_16x16x32_bf16(ah, bh, acc, 0, 0, 0);
                acc = __builtin_amdgcn_mfma_f32_16x16x32_bf16(al, bh, acc, 0, 0, 0);
                acc = __builtin_amdgcn_mfma_f32_16x16x32_bf16(ah, bl, acc, 0, 0, 0);
            }
        }

        // ---- finalize in-lane: lane owns (unit ug, batch bg), gates in regs ----
        float ig = sigmoidf_(acc[0] + bs[0]);
        float fg = sigmoidf_(acc[1] + bs[1]);
        float gg = tanhf    (acc[2] + bs[2]);
        float og = sigmoidf_(acc[3] + bs[3]);
        c = fg * c + ig * gg;
        float h_new = og * tanhf(c);

        // head partial: reduce over the 4 quads (units) for this batch
        float p = h_new * wansu;
        p += __shfl_xor(p, 16, 64);
        p += __shfl_xor(p, 32, 64);
        if (t >= OUT0 && q == 0)
            pout[((size_t)(t - OUT0) * 256 + bid) * 64 + bg] = p;

        // h -> bf16 hi/lo into hf[t+1] frag image (agent-scope write-through)
        {
            ushort_t hs = f2bf(h_new);
            ushort_t ls = f2bf(h_new - bf2f(hs));
            int kq = ug & 31, hks = ug >> 5;
            size_t idx = (((size_t)(t + 1) * 32 + hks) * 4 + w) * 512
                       + (((kq >> 3) * 16) + n) * 8 + (kq & 7);
            __hip_atomic_store(&hf_hi[idx], hs, __ATOMIC_RELAXED,
                               __HIP_MEMORY_SCOPE_AGENT);
            __hip_atomic_store(&hf_lo[idx], ls, __ATOMIC_RELAXED,
                               __HIP_MEMORY_SCOPE_AGENT);
        }

        if (t == NSTEP - 1) break;

        __syncthreads();   // each wave drains its stores (vmcnt 0) before arrive
        if (tid == 0) {
            int r = __hip_atomic_fetch_add(cnt, 1, __ATOMIC_RELAXED,
                                           __HIP_MEMORY_SCOPE_AGENT);
            if (r == 32 * (t + 1) - 1) {
                int s2 = __hip_atomic_fetch_add(scnt, 1, __ATOMIC_RELAXED,
                                                __HIP_MEMORY_SCOPE_AGENT);
                if (s2 == 8 * (t + 1) - 1)
                    __hip_atomic_store(go, t + 1, __ATOMIC_RELAXED,
                                       __HIP_MEMORY_SCOPE_AGENT);
            }
        }
    }
}

// out[b][col] = sum over 256 block partials + bias.
__global__ __launch_bounds__(256) void finalize_mfma(
    const float* __restrict__ pout, const float* __restrict__ b_ans,
    float* __restrict__ out)
{
    __shared__ float r[256];
    int col = blockIdx.x;
    int tid = threadIdx.x;
    int b = tid & 63, qq = tid >> 6;
    float s = 0.f;
    for (int i = qq; i < 256; i += 4)
        s += pout[((size_t)col * 256 + i) * 64 + b];
    r[tid] = s;
    __syncthreads();
    if (tid < 64)
        out[tid * NOUT + col] = r[tid] + r[64 + tid] + r[128 + tid] + r[192 + tid]
                              + b_ans[0];
}

// ===================== round-9 proven fallback path =====================
#define NBLK    512
#define NTHR    512
#define REDA_OFF 12288
#define REDB_OFF 14336
#define REDC_OFF 15360
#define C_OFF    15872
#define HEAD_OFF 16000
#define LDS_FLOATS 16128

__global__ __launch_bounds__(256) void init_state(
    const float* __restrict__ h0, const float* __restrict__ c0,
    float* __restrict__ hT, float* __restrict__ cT)
{
    int id = blockIdx.x * 256 + threadIdx.x;
    int u = id >> 6, b = id & 63;
    hT[id] = h0[b * HID + u];
    cT[id] = c0[b * HID + u];
}

__global__ __launch_bounds__(256) void embed_transpose(
    const int* __restrict__ prob, const float* __restrict__ embed,
    float* __restrict__ xT)
{
    __shared__ float xe[64 * 132];
    int t = blockIdx.x;
    int tid = threadIdx.x;
    for (int kt = 0; kt < 4; ++kt) {
        #pragma unroll
        for (int i = 0; i < 8; ++i) {
            int id = tid + i * 256;
            int b  = id >> 5;
            int k4 = id & 31;
            int tok = prob[b * SEQLEN + t];
            float4 v = *(const float4*)(embed + (size_t)tok * EMBED + kt * 128 + k4 * 4);
            *(float4*)(&xe[b * 132 + k4 * 4]) = v;
        }
        __syncthreads();
        #pragma unroll
        for (int i = 0; i < 8; ++i) {
            int id = tid + i * 256;
            int kl = id >> 4;
            int b4 = id & 15;
            float4 v;
            v.x = xe[(b4 * 4 + 0) * 132 + kl];
            v.y = xe[(b4 * 4 + 1) * 132 + kl];
            v.z = xe[(b4 * 4 + 2) * 132 + kl];
            v.w = xe[(b4 * 4 + 3) * 132 + kl];
            *(float4*)(&xT[((size_t)t * EMBED + kt * 128 + kl) * 64 + b4 * 4]) = v;
        }
        __syncthreads();
    }
}

__global__ __launch_bounds__(NTHR, 4) void lstm_persist_hist(
    const float* __restrict__ xT, float* __restrict__ h_hist,
    const float* __restrict__ cT,
    const float* __restrict__ w_ih, const float* __restrict__ w_hh,
    const float* __restrict__ b_ih, const float* __restrict__ b_hh,
    const float* __restrict__ w_ans, float* __restrict__ pout,
    int* __restrict__ bar)
{
    __shared__ float lds[LDS_FLOATS];
    const int tid = threadIdx.x;
    const int bid = blockIdx.x;
    const int b   = tid & 63;
    const int ksl = __builtin_amdgcn_readfirstlane(tid >> 6);
    const int u0  = bid * 2;

    int* sliceCnt = bar + (bid >> 6) * 32;
    int* mySlice  = bar + 256 + (bid >> 6) * 32;
    int* waitGo   = bar + 256 + ksl * 32;

    for (int idx = tid; idx < 12288; idx += NTHR) {
        int r  = idx / 1536;
        int k  = idx - r * 1536;
        int u2 = r & 1, gate = r >> 1;
        int row = gate * HID + u0 + u2;
        float v = (k < EMBED) ? w_ih[(size_t)row * EMBED + k]
                              : w_hh[(size_t)row * HID + (k - EMBED)];
        lds[(u2 * 1536 + k) * 4 + gate] = v;
    }
    if (tid < 128) lds[C_OFF + tid] = cT[u0 * 64 + tid];

    float bias[2][4], wans[2];
    #pragma unroll
    for (int uu = 0; uu < 2; ++uu) {
        #pragma unroll
        for (int j = 0; j < 4; ++j) {
            int rj = j * HID + u0 + uu;
            bias[uu][j] = b_ih[rj] + b_hh[rj];
        }
        wans[uu] = w_ans[u0 + uu];
    }
    __syncthreads();

    for (int t = 0; t < NSTEP; ++t) {
        const float* xt = xT + (size_t)t * EMBED * 64;
        const float* ht = h_hist + (size_t)t * HID * 64;
        float* hn_buf   = h_hist + (size_t)(t + 1) * HID * 64;

        float acc[2][4];
        #pragma unroll
        for (int uu = 0; uu < 2; ++uu)
            #pragma unroll
            for (int j = 0; j < 4; ++j) acc[uu][j] = 0.f;

        const int kx0 = ksl * 64;
        #pragma unroll 4
        for (int g = 0; g < 16; ++g) {
            const int k = kx0 + g * 4;
            float xv[4];
            #pragma unroll
            for (int i = 0; i < 4; ++i) xv[i] = xt[(size_t)(k + i) * 64 + b];
            #pragma unroll
            for (int i = 0; i < 4; ++i) {
                float4 wa = *(const float4*)&lds[(0 * 1536 + k + i) * 4];
                float4 wb = *(const float4*)&lds[(1 * 1536 + k + i) * 4];
                acc[0][0] = fmaf(wa.x, xv[i], acc[0][0]);
                acc[0][1] = fmaf(wa.y, xv[i], acc[0][1]);
                acc[0][2] = fmaf(wa.z, xv[i], acc[0][2]);
                acc[0][3] = fmaf(wa.w, xv[i], acc[0][3]);
                acc[1][0] = fmaf(wb.x, xv[i], acc[1][0]);
                acc[1][1] = fmaf(wb.y, xv[i], acc[1][1]);
                acc[1][2] = fmaf(wb.z, xv[i], acc[1][2]);
                acc[1][3] = fmaf(wb.w, xv[i], acc[1][3]);
            }
        }

        if (t > 0) {
            while (__hip_atomic_load(waitGo, __ATOMIC_RELAXED,
                                     __HIP_MEMORY_SCOPE_AGENT) < t)
                __builtin_amdgcn_s_sleep(4);
            __builtin_amdgcn_fence(__ATOMIC_ACQUIRE, "workgroup");
        }

        const int kh0 = ksl * 128;
        #pragma unroll 4
        for (int g = 0; g < 32; ++g) {
            const int kh = kh0 + g * 4;
            float hv[4];
            #pragma unroll
            for (int i = 0; i < 4; ++i)
                hv[i] = ht[(size_t)(kh + i) * 64 + b];
            #pragma unroll
            for (int i = 0; i < 4; ++i) {
                const int kw = EMBED + kh + i;
                float4 wa = *(const float4*)&lds[(0 * 1536 + kw) * 4];
                float4 wb = *(const float4*)&lds[(1 * 1536 + kw) * 4];
                acc[0][0] = fmaf(wa.x, hv[i], acc[0][0]);
                acc[0][1] = fmaf(wa.y, hv[i], acc[0][1]);
                acc[0][2] = fmaf(wa.z, hv[i], acc[0][2]);
                acc[0][3] = fmaf(wa.w, hv[i], acc[0][3]);
                acc[1][0] = fmaf(wb.x, hv[i], acc[1][0]);
                acc[1][1] = fmaf(wb.y, hv[i], acc[1][1]);
                acc[1][2] = fmaf(wb.z, hv[i], acc[1][2]);
                acc[1][3] = fmaf(wb.w, hv[i], acc[1][3]);
            }
        }

        if (ksl >= 4) {
            #pragma unroll
            for (int uu = 0; uu < 2; ++uu)
                #pragma unroll
                for (int j = 0; j < 4; ++j)
                    lds[REDA_OFF + (((ksl - 4) * 8) + uu * 4 + j) * 64 + b] = acc[uu][j];
        }
        __syncthreads();
        if (ksl < 4) {
            #pragma unroll
            for (int uu = 0; uu < 2; ++uu)
                #pragma unroll
                for (int j = 0; j < 4; ++j)
                    acc[uu][j] += lds[REDA_OFF + ((ksl * 8) + uu * 4 + j) * 64 + b];
        }
        if (ksl == 2 || ksl == 3) {
            #pragma unroll
            for (int uu = 0; uu < 2; ++uu)
                #pragma unroll
                for (int j = 0; j < 4; ++j)
                    lds[REDB_OFF + (((ksl - 2) * 8) + uu * 4 + j) * 64 + b] = acc[uu][j];
        }
        __syncthreads();
        if (ksl < 2) {
            #pragma unroll
            for (int uu = 0; uu < 2; ++uu)
                #pragma unroll
                for (int j = 0; j < 4; ++j)
                    acc[uu][j] += lds[REDB_OFF + ((ksl * 8) + uu * 4 + j) * 64 + b];
        }
        if (ksl == 0) {
            #pragma unroll
            for (int j = 0; j < 4; ++j)
                lds[REDC_OFF + j * 64 + b] = acc[1][j];
        }
        if (ksl == 1) {
            #pragma unroll
            for (int j = 0; j < 4; ++j)
                lds[REDC_OFF + (4 + j) * 64 + b] = acc[0][j];
        }
        __syncthreads();
        if (ksl < 2) {
            const int uu = ksl;
            float s[4];
            if (ksl == 0) {
                #pragma unroll
                for (int j = 0; j < 4; ++j)
                    s[j] = acc[0][j] + lds[REDC_OFF + (4 + j) * 64 + b];
            } else {
                #pragma unroll
                for (int j = 0; j < 4; ++j)
                    s[j] = acc[1][j] + lds[REDC_OFF + j * 64 + b];
            }
            float i_g = sigmoidf_(s[0] + bias[uu][0]);
            float f_g = sigmoidf_(s[1] + bias[uu][1]);
            float g_g = tanhf   (s[2] + bias[uu][2]);
            float o_g = sigmoidf_(s[3] + bias[uu][3]);
            float c_old = lds[C_OFF + uu * 64 + b];
            float c_new = f_g * c_old + i_g * g_g;
            float h_new = o_g * tanhf(c_new);
            lds[C_OFF + uu * 64 + b] = c_new;
            __hip_atomic_store(&hn_buf[(u0 + uu) * 64 + b], h_new,
                               __ATOMIC_RELAXED, __HIP_MEMORY_SCOPE_AGENT);
            lds[HEAD_OFF + uu * 64 + b] = h_new * wans[uu];
        }

        __syncthreads();
        if (t >= OUT0 && tid < 64) {
            pout[((size_t)(t - OUT0) * NBLK + bid) * 64 + tid] =
                lds[HEAD_OFF + tid] + lds[HEAD_OFF + 64 + tid];
        }
        if (t == NSTEP - 1) break;
        if (tid == 0) {
            int r = __hip_atomic_fetch_add(sliceCnt, 1, __ATOMIC_RELAXED,
                                           __HIP_MEMORY_SCOPE_AGENT);
            if (r == 64 * (t + 1) - 1)
                __hip_atomic_store(mySlice, t + 1, __ATOMIC_RELAXED,
                                   __HIP_MEMORY_SCOPE_AGENT);
        }
    }
}

__global__ __launch_bounds__(256) void finalize_persist(
    const float* __restrict__ pout, const float* __restrict__ b_ans,
    float* __restrict__ out)
{
    __shared__ float r[256];
    int col = blockIdx.x;
    int tid = threadIdx.x;
    int b = tid & 63, qq = tid >> 6;
    float s = 0.f;
    for (int i = qq; i < NBLK; i += 4)
        s += pout[((size_t)col * NBLK + i) * 64 + b];
    r[tid] = s;
    __syncthreads();
    if (tid < 64)
        out[tid * NOUT + col] = r[tid] + r[64 + tid] + r[128 + tid] + r[192 + tid]
                              + b_ans[0];
}

extern "C" void kernel_launch(void* const* d_in, const int* in_sizes, int n_in,
                              void* d_out, int out_size, void* d_ws, size_t ws_size,
                              hipStream_t stream)
{
    const int*   prob  = (const int*)  d_in[0];
    const float* embed = (const float*)d_in[2];
    const float* w_ih  = (const float*)d_in[3];
    const float* w_hh  = (const float*)d_in[4];
    const float* b_ih  = (const float*)d_in[5];
    const float* b_hh  = (const float*)d_in[6];
    const float* w_ans = (const float*)d_in[7];
    const float* b_ans = (const float*)d_in[8];
    const float* h0    = (const float*)d_in[9];
    const float* c0    = (const float*)d_in[10];

    // ---- MFMA-path ws layout (bytes) ----
    char* W = (char*)d_ws;
    float*    cT_m  = (float*)   (W);              // 262,144 B
    float*    poutm = (float*)   (W + 262144);     // 4,063,232 B
    ushort_t* xf_hi = (ushort_t*)(W + 4325376);    // 8,323,072 B
    ushort_t* xf_lo = (ushort_t*)(W + 12648448);   // 8,323,072 B
    ushort_t* hf_hi = (ushort_t*)(W + 20971520);   // 16,777,216 B
    ushort_t* hf_lo = (ushort_t*)(W + 37748736);   // 16,777,216 B
    int*      bar_m = (int*)     (W + 54525952);   // 2,048 B

    hipError_t err = hipFuncSetAttribute(
        (const void*)lstm_mfma,
        hipFuncAttributeMaxDynamicSharedMemorySize, 98304);

    if (err == hipSuccess) {
        hipMemsetAsync(bar_m, 0, 2048, stream);
        init_mfma<<<256, 256, 0, stream>>>(h0, c0, cT_m, hf_hi, hf_lo);
        embed_frag<<<NSTEP, 256, 0, stream>>>(prob, embed, xf_hi, xf_lo);

        void* args[] = {
            (void*)&xf_hi, (void*)&xf_lo, (void*)&hf_hi, (void*)&hf_lo,
            (void*)&cT_m, (void*)&w_ih, (void*)&w_hh, (void*)&b_ih,
            (void*)&b_hh, (void*)&w_ans, (void*)&poutm, (void*)&bar_m
        };
        err = hipLaunchCooperativeKernel((const void*)lstm_mfma,
                                         dim3(256), dim3(256),
                                         args, 98304, stream);
        if (err == hipSuccess) {
            finalize_mfma<<<NOUT, 256, 0, stream>>>(poutm, b_ans, (float*)d_out);
            return;
        }
    }

    // ---- fallback: round-9 proven path (aliases the same ws region) ----
    float* ws     = (float*)d_ws;
    float* cT     = ws;                    // 65,536 fl
    float* pout   = ws + 65536;            // 2,031,616 fl
    float* xT     = ws + 2097152;          // 4,161,536 fl
    float* h_hist = ws + 6258688;          // 8,388,608 fl
    int*   bar    = (int*)(ws + 14647296);

    hipMemsetAsync(bar, 0, 2048, stream);
    init_state<<<256, 256, 0, stream>>>(h0, c0, h_hist, cT);
    embed_transpose<<<NSTEP, 256, 0, stream>>>(prob, embed, xT);

    void* args9[] = {
        (void*)&xT, (void*)&h_hist, (void*)&cT,
        (void*)&w_ih, (void*)&w_hh, (void*)&b_ih, (void*)&b_hh,
        (void*)&w_ans, (void*)&pout, (void*)&bar
    };
    hipLaunchCooperativeKernel((const void*)lstm_persist_hist,
                               dim3(NBLK), dim3(NTHR), args9, 0, stream);
    finalize_persist<<<NOUT, 256, 0, stream>>>(pout, b_ans, (float*)d_out);
}

// Round 12
// 911.082 us; speedup vs baseline: 3.2454x; 1.3736x over previous
//
#include <hip/hip_runtime.h>
#include <math.h>

#define BATCH   64
#define SEQLEN  128
#define EMBED   512
#define HID     1024
#define NSTEP   127
#define OUT0    65
#define NOUT    62

typedef unsigned short ushort_t;
typedef __attribute__((ext_vector_type(8))) __bf16 bf16x8;
typedef __attribute__((ext_vector_type(4))) float  f32x4;

__device__ __forceinline__ float sigmoidf_(float x) { return 1.f / (1.f + expf(-x)); }

__device__ __forceinline__ ushort_t f2bf(float f) {
    unsigned u = __builtin_bit_cast(unsigned, f);
    unsigned r = (u + 0x7FFFu + ((u >> 16) & 1u)) >> 16;   // round-to-nearest-even
    return (ushort_t)r;
}
__device__ __forceinline__ float bf2f(ushort_t s) {
    unsigned u = ((unsigned)s) << 16;
    return __builtin_bit_cast(float, u);
}

// ===================== MFMA path prep =====================

__global__ __launch_bounds__(256) void init_mfma(
    const float* __restrict__ h0, const float* __restrict__ c0,
    float* __restrict__ cT, ushort_t* __restrict__ hf_hi, ushort_t* __restrict__ hf_lo)
{
    int id = blockIdx.x * 256 + threadIdx.x;   // u*64+b
    int u = id >> 6, b = id & 63;
    cT[id] = c0[b * HID + u];
    float h = h0[b * HID + u];
    ushort_t hs = f2bf(h);
    ushort_t ls = f2bf(h - bf2f(hs));
    size_t idx = (((size_t)(u >> 5)) * 4 + (b >> 4)) * 512
               + ((((u & 31) >> 3) * 16) + (b & 15)) * 8 + (u & 7);
    hf_hi[idx] = hs;
    hf_lo[idx] = ls;
}

__global__ __launch_bounds__(256) void embed_frag(
    const int* __restrict__ prob, const float* __restrict__ embed,
    ushort_t* __restrict__ xf_hi, ushort_t* __restrict__ xf_lo)
{
    int t = blockIdx.x;
    for (int e = threadIdx.x; e < 64 * 512; e += 256) {
        int k = e & 511, b = e >> 9;
        int tok = prob[b * SEQLEN + t];
        float f = embed[(size_t)tok * EMBED + k];
        ushort_t hs = f2bf(f);
        ushort_t ls = f2bf(f - bf2f(hs));
        size_t idx = (((size_t)t * 16 + (k >> 5)) * 4 + (b >> 4)) * 512
                   + ((((k & 31) >> 3) * 16) + (b & 15)) * 8 + (k & 7);
        xf_hi[idx] = hs;
        xf_lo[idx] = ls;
    }
}

// ===================== MFMA persistent kernel (r12: 8 waves, K-split) ========
// 256 blocks x 512 thr (1 block/CU, 8 waves = 25% occ). Block = 4 units =
// 16 gate-rows (MFMA M-tile). Wave w: N-tile wn=w&3 (batches wn*16..+15),
// K-half kh=w>>2. Per wave: x phase 8 ksteps, h phase 16 ksteps, x3 MFMA
// (bf16x3: Whi*Xhi + Wlo*Xhi + Whi*Xlo, fp32 acc). Explicit 1-deep B-frag
// prefetch breaks load->mfma serialization (r11: VGPR=36, no lookahead).
// Pair (w, w+4) reduced via LDS; finalize in waves 0..3 in-lane.
__global__ __launch_bounds__(512) void lstm_mfma(
    const ushort_t* __restrict__ xf_hi, const ushort_t* __restrict__ xf_lo,
    ushort_t* __restrict__ hf_hi, ushort_t* __restrict__ hf_lo,
    const float* __restrict__ cT,
    const float* __restrict__ w_ih, const float* __restrict__ w_hh,
    const float* __restrict__ b_ih, const float* __restrict__ b_hh,
    const float* __restrict__ w_ans, float* __restrict__ pout,
    int* __restrict__ bar)
{
    extern __shared__ ushort_t smem[];
    ushort_t* a_hi = smem;                      // [ks 48][512]  (48 KB)
    ushort_t* a_lo = smem + 48 * 512;           // 48 KB
    float*    red  = (float*)(smem + 96 * 512); // 4 KB pair-reduce

    const int tid = threadIdx.x;
    const int bid = blockIdx.x;
    const int w   = tid >> 6;        // 0..7
    const int wn  = w & 3;           // N-tile
    const int kh  = w >> 2;          // K-half
    const int L   = tid & 63;
    const int n   = L & 15;
    const int q   = L >> 4;
    const int u0  = bid * 4;
    const int ug  = u0 + q;
    const int bg  = wn * 16 + n;

    int* cnt  = bar + (bid & 7) * 32;
    int* scnt = bar + 256;
    int* go   = bar + 288;

    // ---- one-time: weight split -> A-frag LDS image ----
    for (int m = 0; m < 16; ++m) {
        int unit = m >> 2, gate = m & 3;
        size_t rowg = (size_t)gate * HID + u0 + unit;
        #pragma unroll
        for (int i = 0; i < 3; ++i) {
            int k = tid + i * 512;                 // 0..1535
            float f = (k < EMBED) ? w_ih[rowg * EMBED + k]
                                  : w_hh[rowg * HID + (k - EMBED)];
            ushort_t hs = f2bf(f);
            ushort_t ls = f2bf(f - bf2f(hs));
            int off = (k >> 5) * 512 + (((k & 31) >> 3) * 16 + m) * 8 + (k & 7);
            a_hi[off] = hs;
            a_lo[off] = ls;
        }
    }

    float c = cT[ug * 64 + bg];
    float bs[4];
    #pragma unroll
    for (int j = 0; j < 4; ++j) bs[j] = b_ih[j * HID + ug] + b_hh[j * HID + ug];
    const float wansu = w_ans[ug];
    __syncthreads();

    for (int t = 0; t < NSTEP; ++t) {
        f32x4 acc = {0.f, 0.f, 0.f, 0.f};

        // ---- x phase: this wave's 8 ksteps (independent of h(t-1)) ----
        {
            const ushort_t* xh = xf_hi + (((size_t)t * 16 + kh * 8) * 4 + wn) * 512 + L * 8;
            const ushort_t* xl = xf_lo + (((size_t)t * 16 + kh * 8) * 4 + wn) * 512 + L * 8;
            bf16x8 bh = *(const bf16x8*)(xh);
            bf16x8 bl = *(const bf16x8*)(xl);
            #pragma unroll
            for (int ks = 0; ks < 8; ++ks) {
                bf16x8 bh1, bl1;
                if (ks < 7) {
                    bh1 = *(const bf16x8*)(xh + (size_t)(ks + 1) * 2048);
                    bl1 = *(const bf16x8*)(xl + (size_t)(ks + 1) * 2048);
                }
                bf16x8 ah = *(const bf16x8*)(a_hi + (kh * 8 + ks) * 512 + L * 8);
                bf16x8 al = *(const bf16x8*)(a_lo + (kh * 8 + ks) * 512 + L * 8);
                acc = __builtin_amdgcn_mfma_f32_16x16x32_bf16(ah, bh, acc, 0, 0, 0);
                acc = __builtin_amdgcn_mfma_f32_16x16x32_bf16(al, bh, acc, 0, 0, 0);
                acc = __builtin_amdgcn_mfma_f32_16x16x32_bf16(ah, bl, acc, 0, 0, 0);
                bh = bh1; bl = bl1;
            }
        }

        // ---- wait for h(t): read-only spin (no cache inv) ----
        if (t > 0) {
            while (__hip_atomic_load(go, __ATOMIC_RELAXED,
                                     __HIP_MEMORY_SCOPE_AGENT) < t)
                __builtin_amdgcn_s_sleep(1);
            __builtin_amdgcn_fence(__ATOMIC_ACQUIRE, "workgroup");
        }

        // ---- h phase: this wave's 16 ksteps, 1-deep prefetch ----
        {
            const ushort_t* hh = hf_hi + (((size_t)t * 32 + kh * 16) * 4 + wn) * 512 + L * 8;
            const ushort_t* hl = hf_lo + (((size_t)t * 32 + kh * 16) * 4 + wn) * 512 + L * 8;
            bf16x8 bh = *(const bf16x8*)(hh);
            bf16x8 bl = *(const bf16x8*)(hl);
            #pragma unroll
            for (int ks = 0; ks < 16; ++ks) {
                bf16x8 bh1, bl1;
                if (ks < 15) {
                    bh1 = *(const bf16x8*)(hh + (size_t)(ks + 1) * 2048);
                    bl1 = *(const bf16x8*)(hl + (size_t)(ks + 1) * 2048);
                }
                bf16x8 ah = *(const bf16x8*)(a_hi + (16 + kh * 16 + ks) * 512 + L * 8);
                bf16x8 al = *(const bf16x8*)(a_lo + (16 + kh * 16 + ks) * 512 + L * 8);
                acc = __builtin_amdgcn_mfma_f32_16x16x32_bf16(ah, bh, acc, 0, 0, 0);
                acc = __builtin_amdgcn_mfma_f32_16x16x32_bf16(al, bh, acc, 0, 0, 0);
                acc = __builtin_amdgcn_mfma_f32_16x16x32_bf16(ah, bl, acc, 0, 0, 0);
                bh = bh1; bl = bl1;
            }
        }

        // ---- K-pair reduce: wave w+4 -> LDS, wave w adds ----
        if (w >= 4)
            *(f32x4*)(red + ((w - 4) * 64 + L) * 4) = acc;
        __syncthreads();

        if (w < 4) {
            f32x4 r = *(const f32x4*)(red + (w * 64 + L) * 4);
            acc += r;

            // ---- finalize in-lane: lane owns (unit ug, batch bg) ----
            float ig = sigmoidf_(acc[0] + bs[0]);
            float fg = sigmoidf_(acc[1] + bs[1]);
            float gg = tanhf    (acc[2] + bs[2]);
            float og = sigmoidf_(acc[3] + bs[3]);
            c = fg * c + ig * gg;
            float h_new = og * tanhf(c);

            float p = h_new * wansu;
            p += __shfl_xor(p, 16, 64);
            p += __shfl_xor(p, 32, 64);
            if (t >= OUT0 && q == 0)
                pout[((size_t)(t - OUT0) * 256 + bid) * 64 + bg] = p;

            ushort_t hs = f2bf(h_new);
            ushort_t ls = f2bf(h_new - bf2f(hs));
            int kq = ug & 31, hks = ug >> 5;
            size_t idx = (((size_t)(t + 1) * 32 + hks) * 4 + wn) * 512
                       + (((kq >> 3) * 16) + n) * 8 + (kq & 7);
            __hip_atomic_store(&hf_hi[idx], hs, __ATOMIC_RELAXED,
                               __HIP_MEMORY_SCOPE_AGENT);
            __hip_atomic_store(&hf_lo[idx], ls, __ATOMIC_RELAXED,
                               __HIP_MEMORY_SCOPE_AGENT);
        }

        if (t == NSTEP - 1) break;

        __syncthreads();   // drains producer stores (vmcnt 0) before arrive
        if (tid == 0) {
            int r = __hip_atomic_fetch_add(cnt, 1, __ATOMIC_RELAXED,
                                           __HIP_MEMORY_SCOPE_AGENT);
            if (r == 32 * (t + 1) - 1) {
                int s2 = __hip_atomic_fetch_add(scnt, 1, __ATOMIC_RELAXED,
                                                __HIP_MEMORY_SCOPE_AGENT);
                if (s2 == 8 * (t + 1) - 1)
                    __hip_atomic_store(go, t + 1, __ATOMIC_RELAXED,
                                       __HIP_MEMORY_SCOPE_AGENT);
            }
        }
    }
}

// out[b][col] = sum over 256 block partials + bias.
__global__ __launch_bounds__(256) void finalize_mfma(
    const float* __restrict__ pout, const float* __restrict__ b_ans,
    float* __restrict__ out)
{
    __shared__ float r[256];
    int col = blockIdx.x;
    int tid = threadIdx.x;
    int b = tid & 63, qq = tid >> 6;
    float s = 0.f;
    for (int i = qq; i < 256; i += 4)
        s += pout[((size_t)col * 256 + i) * 64 + b];
    r[tid] = s;
    __syncthreads();
    if (tid < 64)
        out[tid * NOUT + col] = r[tid] + r[64 + tid] + r[128 + tid] + r[192 + tid]
                              + b_ans[0];
}

// ===================== round-9 proven fallback path =====================
#define NBLK    512
#define NTHR    512
#define REDA_OFF 12288
#define REDB_OFF 14336
#define REDC_OFF 15360
#define C_OFF    15872
#define HEAD_OFF 16000
#define LDS_FLOATS 16128

__global__ __launch_bounds__(256) void init_state(
    const float* __restrict__ h0, const float* __restrict__ c0,
    float* __restrict__ hT, float* __restrict__ cT)
{
    int id = blockIdx.x * 256 + threadIdx.x;
    int u = id >> 6, b = id & 63;
    hT[id] = h0[b * HID + u];
    cT[id] = c0[b * HID + u];
}

__global__ __launch_bounds__(256) void embed_transpose(
    const int* __restrict__ prob, const float* __restrict__ embed,
    float* __restrict__ xT)
{
    __shared__ float xe[64 * 132];
    int t = blockIdx.x;
    int tid = threadIdx.x;
    for (int kt = 0; kt < 4; ++kt) {
        #pragma unroll
        for (int i = 0; i < 8; ++i) {
            int id = tid + i * 256;
            int b  = id >> 5;
            int k4 = id & 31;
            int tok = prob[b * SEQLEN + t];
            float4 v = *(const float4*)(embed + (size_t)tok * EMBED + kt * 128 + k4 * 4);
            *(float4*)(&xe[b * 132 + k4 * 4]) = v;
        }
        __syncthreads();
        #pragma unroll
        for (int i = 0; i < 8; ++i) {
            int id = tid + i * 256;
            int kl = id >> 4;
            int b4 = id & 15;
            float4 v;
            v.x = xe[(b4 * 4 + 0) * 132 + kl];
            v.y = xe[(b4 * 4 + 1) * 132 + kl];
            v.z = xe[(b4 * 4 + 2) * 132 + kl];
            v.w = xe[(b4 * 4 + 3) * 132 + kl];
            *(float4*)(&xT[((size_t)t * EMBED + kt * 128 + kl) * 64 + b4 * 4]) = v;
        }
        __syncthreads();
    }
}

__global__ __launch_bounds__(NTHR, 4) void lstm_persist_hist(
    const float* __restrict__ xT, float* __restrict__ h_hist,
    const float* __restrict__ cT,
    const float* __restrict__ w_ih, const float* __restrict__ w_hh,
    const float* __restrict__ b_ih, const float* __restrict__ b_hh,
    const float* __restrict__ w_ans, float* __restrict__ pout,
    int* __restrict__ bar)
{
    __shared__ float lds[LDS_FLOATS];
    const int tid = threadIdx.x;
    const int bid = blockIdx.x;
    const int b   = tid & 63;
    const int ksl = __builtin_amdgcn_readfirstlane(tid >> 6);
    const int u0  = bid * 2;

    int* sliceCnt = bar + (bid >> 6) * 32;
    int* mySlice  = bar + 256 + (bid >> 6) * 32;
    int* waitGo   = bar + 256 + ksl * 32;

    for (int idx = tid; idx < 12288; idx += NTHR) {
        int r  = idx / 1536;
        int k  = idx - r * 1536;
        int u2 = r & 1, gate = r >> 1;
        int row = gate * HID + u0 + u2;
        float v = (k < EMBED) ? w_ih[(size_t)row * EMBED + k]
                              : w_hh[(size_t)row * HID + (k - EMBED)];
        lds[(u2 * 1536 + k) * 4 + gate] = v;
    }
    if (tid < 128) lds[C_OFF + tid] = cT[u0 * 64 + tid];

    float bias[2][4], wans[2];
    #pragma unroll
    for (int uu = 0; uu < 2; ++uu) {
        #pragma unroll
        for (int j = 0; j < 4; ++j) {
            int rj = j * HID + u0 + uu;
            bias[uu][j] = b_ih[rj] + b_hh[rj];
        }
        wans[uu] = w_ans[u0 + uu];
    }
    __syncthreads();

    for (int t = 0; t < NSTEP; ++t) {
        const float* xt = xT + (size_t)t * EMBED * 64;
        const float* ht = h_hist + (size_t)t * HID * 64;
        float* hn_buf   = h_hist + (size_t)(t + 1) * HID * 64;

        float acc[2][4];
        #pragma unroll
        for (int uu = 0; uu < 2; ++uu)
            #pragma unroll
            for (int j = 0; j < 4; ++j) acc[uu][j] = 0.f;

        const int kx0 = ksl * 64;
        #pragma unroll 4
        for (int g = 0; g < 16; ++g) {
            const int k = kx0 + g * 4;
            float xv[4];
            #pragma unroll
            for (int i = 0; i < 4; ++i) xv[i] = xt[(size_t)(k + i) * 64 + b];
            #pragma unroll
            for (int i = 0; i < 4; ++i) {
                float4 wa = *(const float4*)&lds[(0 * 1536 + k + i) * 4];
                float4 wb = *(const float4*)&lds[(1 * 1536 + k + i) * 4];
                acc[0][0] = fmaf(wa.x, xv[i], acc[0][0]);
                acc[0][1] = fmaf(wa.y, xv[i], acc[0][1]);
                acc[0][2] = fmaf(wa.z, xv[i], acc[0][2]);
                acc[0][3] = fmaf(wa.w, xv[i], acc[0][3]);
                acc[1][0] = fmaf(wb.x, xv[i], acc[1][0]);
                acc[1][1] = fmaf(wb.y, xv[i], acc[1][1]);
                acc[1][2] = fmaf(wb.z, xv[i], acc[1][2]);
                acc[1][3] = fmaf(wb.w, xv[i], acc[1][3]);
            }
        }

        if (t > 0) {
            while (__hip_atomic_load(waitGo, __ATOMIC_RELAXED,
                                     __HIP_MEMORY_SCOPE_AGENT) < t)
                __builtin_amdgcn_s_sleep(4);
            __builtin_amdgcn_fence(__ATOMIC_ACQUIRE, "workgroup");
        }

        const int kh0 = ksl * 128;
        #pragma unroll 4
        for (int g = 0; g < 32; ++g) {
            const int kh = kh0 + g * 4;
            float hv[4];
            #pragma unroll
            for (int i = 0; i < 4; ++i)
                hv[i] = ht[(size_t)(kh + i) * 64 + b];
            #pragma unroll
            for (int i = 0; i < 4; ++i) {
                const int kw = EMBED + kh + i;
                float4 wa = *(const float4*)&lds[(0 * 1536 + kw) * 4];
                float4 wb = *(const float4*)&lds[(1 * 1536 + kw) * 4];
                acc[0][0] = fmaf(wa.x, hv[i], acc[0][0]);
                acc[0][1] = fmaf(wa.y, hv[i], acc[0][1]);
                acc[0][2] = fmaf(wa.z, hv[i], acc[0][2]);
                acc[0][3] = fmaf(wa.w, hv[i], acc[0][3]);
                acc[1][0] = fmaf(wb.x, hv[i], acc[1][0]);
                acc[1][1] = fmaf(wb.y, hv[i], acc[1][1]);
                acc[1][2] = fmaf(wb.z, hv[i], acc[1][2]);
                acc[1][3] = fmaf(wb.w, hv[i], acc[1][3]);
            }
        }

        if (ksl >= 4) {
            #pragma unroll
            for (int uu = 0; uu < 2; ++uu)
                #pragma unroll
                for (int j = 0; j < 4; ++j)
                    lds[REDA_OFF + (((ksl - 4) * 8) + uu * 4 + j) * 64 + b] = acc[uu][j];
        }
        __syncthreads();
        if (ksl < 4) {
            #pragma unroll
            for (int uu = 0; uu < 2; ++uu)
                #pragma unroll
                for (int j = 0; j < 4; ++j)
                    acc[uu][j] += lds[REDA_OFF + ((ksl * 8) + uu * 4 + j) * 64 + b];
        }
        if (ksl == 2 || ksl == 3) {
            #pragma unroll
            for (int uu = 0; uu < 2; ++uu)
                #pragma unroll
                for (int j = 0; j < 4; ++j)
                    lds[REDB_OFF + (((ksl - 2) * 8) + uu * 4 + j) * 64 + b] = acc[uu][j];
        }
        __syncthreads();
        if (ksl < 2) {
            #pragma unroll
            for (int uu = 0; uu < 2; ++uu)
                #pragma unroll
                for (int j = 0; j < 4; ++j)
                    acc[uu][j] += lds[REDB_OFF + ((ksl * 8) + uu * 4 + j) * 64 + b];
        }
        if (ksl == 0) {
            #pragma unroll
            for (int j = 0; j < 4; ++j)
                lds[REDC_OFF + j * 64 + b] = acc[1][j];
        }
        if (ksl == 1) {
            #pragma unroll
            for (int j = 0; j < 4; ++j)
                lds[REDC_OFF + (4 + j) * 64 + b] = acc[0][j];
        }
        __syncthreads();
        if (ksl < 2) {
            const int uu = ksl;
            float s[4];
            if (ksl == 0) {
                #pragma unroll
                for (int j = 0; j < 4; ++j)
                    s[j] = acc[0][j] + lds[REDC_OFF + (4 + j) * 64 + b];
            } else {
                #pragma unroll
                for (int j = 0; j < 4; ++j)
                    s[j] = acc[1][j] + lds[REDC_OFF + j * 64 + b];
            }
            float i_g = sigmoidf_(s[0] + bias[uu][0]);
            float f_g = sigmoidf_(s[1] + bias[uu][1]);
            float g_g = tanhf   (s[2] + bias[uu][2]);
            float o_g = sigmoidf_(s[3] + bias[uu][3]);
            float c_old = lds[C_OFF + uu * 64 + b];
            float c_new = f_g * c_old + i_g * g_g;
            float h_new = o_g * tanhf(c_new);
            lds[C_OFF + uu * 64 + b] = c_new;
            __hip_atomic_store(&hn_buf[(u0 + uu) * 64 + b], h_new,
                               __ATOMIC_RELAXED, __HIP_MEMORY_SCOPE_AGENT);
            lds[HEAD_OFF + uu * 64 + b] = h_new * wans[uu];
        }

        __syncthreads();
        if (t >= OUT0 && tid < 64) {
            pout[((size_t)(t - OUT0) * NBLK + bid) * 64 + tid] =
                lds[HEAD_OFF + tid] + lds[HEAD_OFF + 64 + tid];
        }
        if (t == NSTEP - 1) break;
        if (tid == 0) {
            int r = __hip_atomic_fetch_add(sliceCnt, 1, __ATOMIC_RELAXED,
                                           __HIP_MEMORY_SCOPE_AGENT);
            if (r == 64 * (t + 1) - 1)
                __hip_atomic_store(mySlice, t + 1, __ATOMIC_RELAXED,
                                   __HIP_MEMORY_SCOPE_AGENT);
        }
    }
}

__global__ __launch_bounds__(256) void finalize_persist(
    const float* __restrict__ pout, const float* __restrict__ b_ans,
    float* __restrict__ out)
{
    __shared__ float r[256];
    int col = blockIdx.x;
    int tid = threadIdx.x;
    int b = tid & 63, qq = tid >> 6;
    float s = 0.f;
    for (int i = qq; i < NBLK; i += 4)
        s += pout[((size_t)col * NBLK + i) * 64 + b];
    r[tid] = s;
    __syncthreads();
    if (tid < 64)
        out[tid * NOUT + col] = r[tid] + r[64 + tid] + r[128 + tid] + r[192 + tid]
                              + b_ans[0];
}

extern "C" void kernel_launch(void* const* d_in, const int* in_sizes, int n_in,
                              void* d_out, int out_size, void* d_ws, size_t ws_size,
                              hipStream_t stream)
{
    const int*   prob  = (const int*)  d_in[0];
    const float* embed = (const float*)d_in[2];
    const float* w_ih  = (const float*)d_in[3];
    const float* w_hh  = (const float*)d_in[4];
    const float* b_ih  = (const float*)d_in[5];
    const float* b_hh  = (const float*)d_in[6];
    const float* w_ans = (const float*)d_in[7];
    const float* b_ans = (const float*)d_in[8];
    const float* h0    = (const float*)d_in[9];
    const float* c0    = (const float*)d_in[10];

    // ---- MFMA-path ws layout (bytes) ----
    char* W = (char*)d_ws;
    float*    cT_m  = (float*)   (W);              // 262,144 B
    float*    poutm = (float*)   (W + 262144);     // 4,063,232 B
    ushort_t* xf_hi = (ushort_t*)(W + 4325376);    // 8,323,072 B
    ushort_t* xf_lo = (ushort_t*)(W + 12648448);   // 8,323,072 B
    ushort_t* hf_hi = (ushort_t*)(W + 20971520);   // 16,777,216 B
    ushort_t* hf_lo = (ushort_t*)(W + 37748736);   // 16,777,216 B
    int*      bar_m = (int*)     (W + 54525952);   // 2,048 B

    const int DYN_LDS = 96 * 1024 + 4096;          // A-frags + pair-reduce

    hipError_t err = hipFuncSetAttribute(
        (const void*)lstm_mfma,
        hipFuncAttributeMaxDynamicSharedMemorySize, DYN_LDS);

    if (err == hipSuccess) {
        hipMemsetAsync(bar_m, 0, 2048, stream);
        init_mfma<<<256, 256, 0, stream>>>(h0, c0, cT_m, hf_hi, hf_lo);
        embed_frag<<<NSTEP, 256, 0, stream>>>(prob, embed, xf_hi, xf_lo);

        void* args[] = {
            (void*)&xf_hi, (void*)&xf_lo, (void*)&hf_hi, (void*)&hf_lo,
            (void*)&cT_m, (void*)&w_ih, (void*)&w_hh, (void*)&b_ih,
            (void*)&b_hh, (void*)&w_ans, (void*)&poutm, (void*)&bar_m
        };
        err = hipLaunchCooperativeKernel((const void*)lstm_mfma,
                                         dim3(256), dim3(512),
                                         args, DYN_LDS, stream);
        if (err == hipSuccess) {
            finalize_mfma<<<NOUT, 256, 0, stream>>>(poutm, b_ans, (float*)d_out);
            return;
        }
    }

    // ---- fallback: round-9 proven path (aliases the same ws region) ----
    float* ws     = (float*)d_ws;
    float* cT     = ws;                    // 65,536 fl
    float* pout   = ws + 65536;            // 2,031,616 fl
    float* xT     = ws + 2097152;          // 4,161,536 fl
    float* h_hist = ws + 6258688;          // 8,388,608 fl
    int*   bar    = (int*)(ws + 14647296);

    hipMemsetAsync(bar, 0, 2048, stream);
    init_state<<<256, 256, 0, stream>>>(h0, c0, h_hist, cT);
    embed_transpose<<<NSTEP, 256, 0, stream>>>(prob, embed, xT);

    void* args9[] = {
        (void*)&xT, (void*)&h_hist, (void*)&cT,
        (void*)&w_ih, (void*)&w_hh, (void*)&b_ih, (void*)&b_hh,
        (void*)&w_ans, (void*)&pout, (void*)&bar
    };
    hipLaunchCooperativeKernel((const void*)lstm_persist_hist,
                               dim3(NBLK), dim3(NTHR), args9, 0, stream);
    finalize_persist<<<NOUT, 256, 0, stream>>>(pout, b_ans, (float*)d_out);
}

// Round 13
// 902.528 us; speedup vs baseline: 3.2761x; 1.0095x over previous
//
#include <hip/hip_runtime.h>
#include <math.h>

#define BATCH   64
#define SEQLEN  128
#define EMBED   512
#define HID     1024
#define NSTEP   127
#define OUT0    65
#define NOUT    62

typedef unsigned short ushort_t;
typedef __attribute__((ext_vector_type(8))) __bf16 bf16x8;
typedef __attribute__((ext_vector_type(4))) float  f32x4;

__device__ __forceinline__ float sigmoidf_(float x) { return 1.f / (1.f + expf(-x)); }

__device__ __forceinline__ ushort_t f2bf(float f) {
    unsigned u = __builtin_bit_cast(unsigned, f);
    unsigned r = (u + 0x7FFFu + ((u >> 16) & 1u)) >> 16;   // round-to-nearest-even
    return (ushort_t)r;
}
__device__ __forceinline__ float bf2f(ushort_t s) {
    unsigned u = ((unsigned)s) << 16;
    return __builtin_bit_cast(float, u);
}

// ===================== MFMA path prep =====================

__global__ __launch_bounds__(256) void init_mfma(
    const float* __restrict__ h0, const float* __restrict__ c0,
    float* __restrict__ cT, ushort_t* __restrict__ hf_hi, ushort_t* __restrict__ hf_lo)
{
    int id = blockIdx.x * 256 + threadIdx.x;   // u*64+b
    int u = id >> 6, b = id & 63;
    cT[id] = c0[b * HID + u];
    float h = h0[b * HID + u];
    ushort_t hs = f2bf(h);
    ushort_t ls = f2bf(h - bf2f(hs));
    size_t idx = (((size_t)(u >> 5)) * 4 + (b >> 4)) * 512
               + ((((u & 31) >> 3) * 16) + (b & 15)) * 8 + (u & 7);
    hf_hi[idx] = hs;
    hf_lo[idx] = ls;
}

// r13: coalesced — thread = (b, k-block-of-8); frag layout keeps k&7
// contiguous so each thread writes two 16B bf16x8 stores (was 16x 2B scatter).
__global__ __launch_bounds__(256) void embed_frag(
    const int* __restrict__ prob, const float* __restrict__ embed,
    ushort_t* __restrict__ xf_hi, ushort_t* __restrict__ xf_lo)
{
    int t = blockIdx.x;
    for (int e = threadIdx.x; e < 4096; e += 256) {
        int b  = e >> 6;         // 0..63
        int kb = e & 63;         // k-block of 8
        int k  = kb * 8;
        int tok = prob[b * SEQLEN + t];
        const float* row = embed + (size_t)tok * EMBED + k;
        float4 f0 = *(const float4*)(row);
        float4 f1 = *(const float4*)(row + 4);
        float fv[8] = { f0.x, f0.y, f0.z, f0.w, f1.x, f1.y, f1.z, f1.w };
        bf16x8 hv, lv;
        #pragma unroll
        for (int i = 0; i < 8; ++i) {
            ushort_t hs = f2bf(fv[i]);
            ushort_t ls = f2bf(fv[i] - bf2f(hs));
            hv[i] = __builtin_bit_cast(__bf16, hs);
            lv[i] = __builtin_bit_cast(__bf16, ls);
        }
        size_t idx = (((size_t)t * 16 + (kb >> 2)) * 4 + (b >> 4)) * 512
                   + (((kb & 3) * 16) + (b & 15)) * 8;
        *(bf16x8*)(xf_hi + idx) = hv;
        *(bf16x8*)(xf_lo + idx) = lv;
    }
}

// ===================== MFMA persistent kernel (r13: 16 waves, K-quarter) =====
// 256 blocks x 1024 thr (1 block/CU, 16 waves = 48% occ). Block = 4 units =
// 16 gate-rows (MFMA M-tile). Wave w: N-tile wn=w&3, K-quarter kq=w>>2.
// Per wave: x 4 ksteps, h 8 ksteps, x3 MFMA (bf16x3), 1-deep B prefetch.
// Binary reduce: kq>=2 -> REDA, kq1 -> REDB, kq0 finalizes in-lane.
__global__ __launch_bounds__(1024) void lstm_mfma(
    const ushort_t* __restrict__ xf_hi, const ushort_t* __restrict__ xf_lo,
    ushort_t* __restrict__ hf_hi, ushort_t* __restrict__ hf_lo,
    const float* __restrict__ cT,
    const float* __restrict__ w_ih, const float* __restrict__ w_hh,
    const float* __restrict__ b_ih, const float* __restrict__ b_hh,
    const float* __restrict__ w_ans, float* __restrict__ pout,
    int* __restrict__ bar)
{
    extern __shared__ ushort_t smem[];
    ushort_t* a_hi = smem;                       // [ks 48][512] 48 KB
    ushort_t* a_lo = smem + 48 * 512;            // 48 KB
    float*    redA = (float*)(smem + 96 * 512);  // 8 KB (8 waves x 64 x f32x4)
    float*    redB = redA + 2048;                // 4 KB (4 waves x 64 x f32x4)

    const int tid = threadIdx.x;
    const int bid = blockIdx.x;
    const int w   = tid >> 6;        // 0..15
    const int wn  = w & 3;           // N-tile
    const int kq  = w >> 2;          // K-quarter 0..3
    const int L   = tid & 63;
    const int n   = L & 15;
    const int q   = L >> 4;
    const int u0  = bid * 4;
    const int ug  = u0 + q;
    const int bg  = wn * 16 + n;

    int* cnt  = bar + (bid & 7) * 32;
    int* scnt = bar + 256;
    int* go   = bar + 288;

    // ---- one-time: weight split -> A-frag LDS image ----
    for (int m = 0; m < 16; ++m) {
        int unit = m >> 2, gate = m & 3;
        size_t rowg = (size_t)gate * HID + u0 + unit;
        for (int k = tid; k < 1536; k += 1024) {
            float f = (k < EMBED) ? w_ih[rowg * EMBED + k]
                                  : w_hh[rowg * HID + (k - EMBED)];
            ushort_t hs = f2bf(f);
            ushort_t ls = f2bf(f - bf2f(hs));
            int off = (k >> 5) * 512 + (((k & 31) >> 3) * 16 + m) * 8 + (k & 7);
            a_hi[off] = hs;
            a_lo[off] = ls;
        }
    }

    float c = cT[ug * 64 + bg];
    float bs[4];
    #pragma unroll
    for (int j = 0; j < 4; ++j) bs[j] = b_ih[j * HID + ug] + b_hh[j * HID + ug];
    const float wansu = w_ans[ug];
    __syncthreads();

    for (int t = 0; t < NSTEP; ++t) {
        f32x4 acc = {0.f, 0.f, 0.f, 0.f};

        // ---- x phase: this wave's 4 ksteps (independent of h(t-1)) ----
        {
            const ushort_t* xh = xf_hi + (((size_t)t * 16 + kq * 4) * 4 + wn) * 512 + L * 8;
            const ushort_t* xl = xf_lo + (((size_t)t * 16 + kq * 4) * 4 + wn) * 512 + L * 8;
            bf16x8 bh = *(const bf16x8*)(xh);
            bf16x8 bl = *(const bf16x8*)(xl);
            #pragma unroll
            for (int ks = 0; ks < 4; ++ks) {
                bf16x8 bh1, bl1;
                if (ks < 3) {
                    bh1 = *(const bf16x8*)(xh + (size_t)(ks + 1) * 2048);
                    bl1 = *(const bf16x8*)(xl + (size_t)(ks + 1) * 2048);
                }
                bf16x8 ah = *(const bf16x8*)(a_hi + (kq * 4 + ks) * 512 + L * 8);
                bf16x8 al = *(const bf16x8*)(a_lo + (kq * 4 + ks) * 512 + L * 8);
                acc = __builtin_amdgcn_mfma_f32_16x16x32_bf16(ah, bh, acc, 0, 0, 0);
                acc = __builtin_amdgcn_mfma_f32_16x16x32_bf16(al, bh, acc, 0, 0, 0);
                acc = __builtin_amdgcn_mfma_f32_16x16x32_bf16(ah, bl, acc, 0, 0, 0);
                bh = bh1; bl = bl1;
            }
        }

        // ---- wait for h(t): read-only spin (no cache inv) ----
        if (t > 0) {
            while (__hip_atomic_load(go, __ATOMIC_RELAXED,
                                     __HIP_MEMORY_SCOPE_AGENT) < t)
                __builtin_amdgcn_s_sleep(1);
            __builtin_amdgcn_fence(__ATOMIC_ACQUIRE, "workgroup");
        }

        // ---- h phase: this wave's 8 ksteps, 1-deep prefetch ----
        {
            const ushort_t* hh = hf_hi + (((size_t)t * 32 + kq * 8) * 4 + wn) * 512 + L * 8;
            const ushort_t* hl = hf_lo + (((size_t)t * 32 + kq * 8) * 4 + wn) * 512 + L * 8;
            bf16x8 bh = *(const bf16x8*)(hh);
            bf16x8 bl = *(const bf16x8*)(hl);
            #pragma unroll
            for (int ks = 0; ks < 8; ++ks) {
                bf16x8 bh1, bl1;
                if (ks < 7) {
                    bh1 = *(const bf16x8*)(hh + (size_t)(ks + 1) * 2048);
                    bl1 = *(const bf16x8*)(hl + (size_t)(ks + 1) * 2048);
                }
                bf16x8 ah = *(const bf16x8*)(a_hi + (16 + kq * 8 + ks) * 512 + L * 8);
                bf16x8 al = *(const bf16x8*)(a_lo + (16 + kq * 8 + ks) * 512 + L * 8);
                acc = __builtin_amdgcn_mfma_f32_16x16x32_bf16(ah, bh, acc, 0, 0, 0);
                acc = __builtin_amdgcn_mfma_f32_16x16x32_bf16(al, bh, acc, 0, 0, 0);
                acc = __builtin_amdgcn_mfma_f32_16x16x32_bf16(ah, bl, acc, 0, 0, 0);
                bh = bh1; bl = bl1;
            }
        }

        // ---- K reduce: kq>=2 -> REDA; kq<2 add; kq1 -> REDB; kq0 adds ----
        if (kq >= 2)
            *(f32x4*)(redA + ((w - 8) * 64 + L) * 4) = acc;
        __syncthreads();
        if (kq < 2) {
            f32x4 r = *(const f32x4*)(redA + (w * 64 + L) * 4);  // (wn,kq) <- (wn,kq+2)
            acc += r;
        }
        if (kq == 1)
            *(f32x4*)(redB + ((w - 4) * 64 + L) * 4) = acc;
        __syncthreads();

        if (kq == 0) {
            f32x4 r = *(const f32x4*)(redB + (w * 64 + L) * 4);
            acc += r;

            // ---- finalize in-lane: lane owns (unit ug, batch bg) ----
            float ig = sigmoidf_(acc[0] + bs[0]);
            float fg = sigmoidf_(acc[1] + bs[1]);
            float gg = tanhf    (acc[2] + bs[2]);
            float og = sigmoidf_(acc[3] + bs[3]);
            c = fg * c + ig * gg;
            float h_new = og * tanhf(c);

            float p = h_new * wansu;
            p += __shfl_xor(p, 16, 64);
            p += __shfl_xor(p, 32, 64);
            if (t >= OUT0 && q == 0)
                pout[((size_t)(t - OUT0) * 256 + bid) * 64 + bg] = p;

            ushort_t hs = f2bf(h_new);
            ushort_t ls = f2bf(h_new - bf2f(hs));
            int kr = ug & 31, hks = ug >> 5;
            size_t idx = (((size_t)(t + 1) * 32 + hks) * 4 + wn) * 512
                       + (((kr >> 3) * 16) + n) * 8 + (kr & 7);
            __hip_atomic_store(&hf_hi[idx], hs, __ATOMIC_RELAXED,
                               __HIP_MEMORY_SCOPE_AGENT);
            __hip_atomic_store(&hf_lo[idx], ls, __ATOMIC_RELAXED,
                               __HIP_MEMORY_SCOPE_AGENT);
        }

        if (t == NSTEP - 1) break;

        __syncthreads();   // drains producer stores (vmcnt 0) before arrive
        if (tid == 0) {
            int r = __hip_atomic_fetch_add(cnt, 1, __ATOMIC_RELAXED,
                                           __HIP_MEMORY_SCOPE_AGENT);
            if (r == 32 * (t + 1) - 1) {
                int s2 = __hip_atomic_fetch_add(scnt, 1, __ATOMIC_RELAXED,
                                                __HIP_MEMORY_SCOPE_AGENT);
                if (s2 == 8 * (t + 1) - 1)
                    __hip_atomic_store(go, t + 1, __ATOMIC_RELAXED,
                                       __HIP_MEMORY_SCOPE_AGENT);
            }
        }
    }
}

// out[b][col] = sum over 256 block partials + bias.
__global__ __launch_bounds__(256) void finalize_mfma(
    const float* __restrict__ pout, const float* __restrict__ b_ans,
    float* __restrict__ out)
{
    __shared__ float r[256];
    int col = blockIdx.x;
    int tid = threadIdx.x;
    int b = tid & 63, qq = tid >> 6;
    float s = 0.f;
    for (int i = qq; i < 256; i += 4)
        s += pout[((size_t)col * 256 + i) * 64 + b];
    r[tid] = s;
    __syncthreads();
    if (tid < 64)
        out[tid * NOUT + col] = r[tid] + r[64 + tid] + r[128 + tid] + r[192 + tid]
                              + b_ans[0];
}

// ===================== round-9 proven fallback path =====================
#define NBLK    512
#define NTHR    512
#define REDA_OFF 12288
#define REDB_OFF 14336
#define REDC_OFF 15360
#define C_OFF    15872
#define HEAD_OFF 16000
#define LDS_FLOATS 16128

__global__ __launch_bounds__(256) void init_state(
    const float* __restrict__ h0, const float* __restrict__ c0,
    float* __restrict__ hT, float* __restrict__ cT)
{
    int id = blockIdx.x * 256 + threadIdx.x;
    int u = id >> 6, b = id & 63;
    hT[id] = h0[b * HID + u];
    cT[id] = c0[b * HID + u];
}

__global__ __launch_bounds__(256) void embed_transpose(
    const int* __restrict__ prob, const float* __restrict__ embed,
    float* __restrict__ xT)
{
    __shared__ float xe[64 * 132];
    int t = blockIdx.x;
    int tid = threadIdx.x;
    for (int kt = 0; kt < 4; ++kt) {
        #pragma unroll
        for (int i = 0; i < 8; ++i) {
            int id = tid + i * 256;
            int b  = id >> 5;
            int k4 = id & 31;
            int tok = prob[b * SEQLEN + t];
            float4 v = *(const float4*)(embed + (size_t)tok * EMBED + kt * 128 + k4 * 4);
            *(float4*)(&xe[b * 132 + k4 * 4]) = v;
        }
        __syncthreads();
        #pragma unroll
        for (int i = 0; i < 8; ++i) {
            int id = tid + i * 256;
            int kl = id >> 4;
            int b4 = id & 15;
            float4 v;
            v.x = xe[(b4 * 4 + 0) * 132 + kl];
            v.y = xe[(b4 * 4 + 1) * 132 + kl];
            v.z = xe[(b4 * 4 + 2) * 132 + kl];
            v.w = xe[(b4 * 4 + 3) * 132 + kl];
            *(float4*)(&xT[((size_t)t * EMBED + kt * 128 + kl) * 64 + b4 * 4]) = v;
        }
        __syncthreads();
    }
}

__global__ __launch_bounds__(NTHR, 4) void lstm_persist_hist(
    const float* __restrict__ xT, float* __restrict__ h_hist,
    const float* __restrict__ cT,
    const float* __restrict__ w_ih, const float* __restrict__ w_hh,
    const float* __restrict__ b_ih, const float* __restrict__ b_hh,
    const float* __restrict__ w_ans, float* __restrict__ pout,
    int* __restrict__ bar)
{
    __shared__ float lds[LDS_FLOATS];
    const int tid = threadIdx.x;
    const int bid = blockIdx.x;
    const int b   = tid & 63;
    const int ksl = __builtin_amdgcn_readfirstlane(tid >> 6);
    const int u0  = bid * 2;

    int* sliceCnt = bar + (bid >> 6) * 32;
    int* mySlice  = bar + 256 + (bid >> 6) * 32;
    int* waitGo   = bar + 256 + ksl * 32;

    for (int idx = tid; idx < 12288; idx += NTHR) {
        int r  = idx / 1536;
        int k  = idx - r * 1536;
        int u2 = r & 1, gate = r >> 1;
        int row = gate * HID + u0 + u2;
        float v = (k < EMBED) ? w_ih[(size_t)row * EMBED + k]
                              : w_hh[(size_t)row * HID + (k - EMBED)];
        lds[(u2 * 1536 + k) * 4 + gate] = v;
    }
    if (tid < 128) lds[C_OFF + tid] = cT[u0 * 64 + tid];

    float bias[2][4], wans[2];
    #pragma unroll
    for (int uu = 0; uu < 2; ++uu) {
        #pragma unroll
        for (int j = 0; j < 4; ++j) {
            int rj = j * HID + u0 + uu;
            bias[uu][j] = b_ih[rj] + b_hh[rj];
        }
        wans[uu] = w_ans[u0 + uu];
    }
    __syncthreads();

    for (int t = 0; t < NSTEP; ++t) {
        const float* xt = xT + (size_t)t * EMBED * 64;
        const float* ht = h_hist + (size_t)t * HID * 64;
        float* hn_buf   = h_hist + (size_t)(t + 1) * HID * 64;

        float acc[2][4];
        #pragma unroll
        for (int uu = 0; uu < 2; ++uu)
            #pragma unroll
            for (int j = 0; j < 4; ++j) acc[uu][j] = 0.f;

        const int kx0 = ksl * 64;
        #pragma unroll 4
        for (int g = 0; g < 16; ++g) {
            const int k = kx0 + g * 4;
            float xv[4];
            #pragma unroll
            for (int i = 0; i < 4; ++i) xv[i] = xt[(size_t)(k + i) * 64 + b];
            #pragma unroll
            for (int i = 0; i < 4; ++i) {
                float4 wa = *(const float4*)&lds[(0 * 1536 + k + i) * 4];
                float4 wb = *(const float4*)&lds[(1 * 1536 + k + i) * 4];
                acc[0][0] = fmaf(wa.x, xv[i], acc[0][0]);
                acc[0][1] = fmaf(wa.y, xv[i], acc[0][1]);
                acc[0][2] = fmaf(wa.z, xv[i], acc[0][2]);
                acc[0][3] = fmaf(wa.w, xv[i], acc[0][3]);
                acc[1][0] = fmaf(wb.x, xv[i], acc[1][0]);
                acc[1][1] = fmaf(wb.y, xv[i], acc[1][1]);
                acc[1][2] = fmaf(wb.z, xv[i], acc[1][2]);
                acc[1][3] = fmaf(wb.w, xv[i], acc[1][3]);
            }
        }

        if (t > 0) {
            while (__hip_atomic_load(waitGo, __ATOMIC_RELAXED,
                                     __HIP_MEMORY_SCOPE_AGENT) < t)
                __builtin_amdgcn_s_sleep(4);
            __builtin_amdgcn_fence(__ATOMIC_ACQUIRE, "workgroup");
        }

        const int kh0 = ksl * 128;
        #pragma unroll 4
        for (int g = 0; g < 32; ++g) {
            const int kh = kh0 + g * 4;
            float hv[4];
            #pragma unroll
            for (int i = 0; i < 4; ++i)
                hv[i] = ht[(size_t)(kh + i) * 64 + b];
            #pragma unroll
            for (int i = 0; i < 4; ++i) {
                const int kw = EMBED + kh + i;
                float4 wa = *(const float4*)&lds[(0 * 1536 + kw) * 4];
                float4 wb = *(const float4*)&lds[(1 * 1536 + kw) * 4];
                acc[0][0] = fmaf(wa.x, hv[i], acc[0][0]);
                acc[0][1] = fmaf(wa.y, hv[i], acc[0][1]);
                acc[0][2] = fmaf(wa.z, hv[i], acc[0][2]);
                acc[0][3] = fmaf(wa.w, hv[i], acc[0][3]);
                acc[1][0] = fmaf(wb.x, hv[i], acc[1][0]);
                acc[1][1] = fmaf(wb.y, hv[i], acc[1][1]);
                acc[1][2] = fmaf(wb.z, hv[i], acc[1][2]);
                acc[1][3] = fmaf(wb.w, hv[i], acc[1][3]);
            }
        }

        if (ksl >= 4) {
            #pragma unroll
            for (int uu = 0; uu < 2; ++uu)
                #pragma unroll
                for (int j = 0; j < 4; ++j)
                    lds[REDA_OFF + (((ksl - 4) * 8) + uu * 4 + j) * 64 + b] = acc[uu][j];
        }
        __syncthreads();
        if (ksl < 4) {
            #pragma unroll
            for (int uu = 0; uu < 2; ++uu)
                #pragma unroll
                for (int j = 0; j < 4; ++j)
                    acc[uu][j] += lds[REDA_OFF + ((ksl * 8) + uu * 4 + j) * 64 + b];
        }
        if (ksl == 2 || ksl == 3) {
            #pragma unroll
            for (int uu = 0; uu < 2; ++uu)
                #pragma unroll
                for (int j = 0; j < 4; ++j)
                    lds[REDB_OFF + (((ksl - 2) * 8) + uu * 4 + j) * 64 + b] = acc[uu][j];
        }
        __syncthreads();
        if (ksl < 2) {
            #pragma unroll
            for (int uu = 0; uu < 2; ++uu)
                #pragma unroll
                for (int j = 0; j < 4; ++j)
                    acc[uu][j] += lds[REDB_OFF + ((ksl * 8) + uu * 4 + j) * 64 + b];
        }
        if (ksl == 0) {
            #pragma unroll
            for (int j = 0; j < 4; ++j)
                lds[REDC_OFF + j * 64 + b] = acc[1][j];
        }
        if (ksl == 1) {
            #pragma unroll
            for (int j = 0; j < 4; ++j)
                lds[REDC_OFF + (4 + j) * 64 + b] = acc[0][j];
        }
        __syncthreads();
        if (ksl < 2) {
            const int uu = ksl;
            float s[4];
            if (ksl == 0) {
                #pragma unroll
                for (int j = 0; j < 4; ++j)
                    s[j] = acc[0][j] + lds[REDC_OFF + (4 + j) * 64 + b];
            } else {
                #pragma unroll
                for (int j = 0; j < 4; ++j)
                    s[j] = acc[1][j] + lds[REDC_OFF + j * 64 + b];
            }
            float i_g = sigmoidf_(s[0] + bias[uu][0]);
            float f_g = sigmoidf_(s[1] + bias[uu][1]);
            float g_g = tanhf   (s[2] + bias[uu][2]);
            float o_g = sigmoidf_(s[3] + bias[uu][3]);
            float c_old = lds[C_OFF + uu * 64 + b];
            float c_new = f_g * c_old + i_g * g_g;
            float h_new = o_g * tanhf(c_new);
            lds[C_OFF + uu * 64 + b] = c_new;
            __hip_atomic_store(&hn_buf[(u0 + uu) * 64 + b], h_new,
                               __ATOMIC_RELAXED, __HIP_MEMORY_SCOPE_AGENT);
            lds[HEAD_OFF + uu * 64 + b] = h_new * wans[uu];
        }

        __syncthreads();
        if (t >= OUT0 && tid < 64) {
            pout[((size_t)(t - OUT0) * NBLK + bid) * 64 + tid] =
                lds[HEAD_OFF + tid] + lds[HEAD_OFF + 64 + tid];
        }
        if (t == NSTEP - 1) break;
        if (tid == 0) {
            int r = __hip_atomic_fetch_add(sliceCnt, 1, __ATOMIC_RELAXED,
                                           __HIP_MEMORY_SCOPE_AGENT);
            if (r == 64 * (t + 1) - 1)
                __hip_atomic_store(mySlice, t + 1, __ATOMIC_RELAXED,
                                   __HIP_MEMORY_SCOPE_AGENT);
        }
    }
}

__global__ __launch_bounds__(256) void finalize_persist(
    const float* __restrict__ pout, const float* __restrict__ b_ans,
    float* __restrict__ out)
{
    __shared__ float r[256];
    int col = blockIdx.x;
    int tid = threadIdx.x;
    int b = tid & 63, qq = tid >> 6;
    float s = 0.f;
    for (int i = qq; i < NBLK; i += 4)
        s += pout[((size_t)col * NBLK + i) * 64 + b];
    r[tid] = s;
    __syncthreads();
    if (tid < 64)
        out[tid * NOUT + col] = r[tid] + r[64 + tid] + r[128 + tid] + r[192 + tid]
                              + b_ans[0];
}

extern "C" void kernel_launch(void* const* d_in, const int* in_sizes, int n_in,
                              void* d_out, int out_size, void* d_ws, size_t ws_size,
                              hipStream_t stream)
{
    const int*   prob  = (const int*)  d_in[0];
    const float* embed = (const float*)d_in[2];
    const float* w_ih  = (const float*)d_in[3];
    const float* w_hh  = (const float*)d_in[4];
    const float* b_ih  = (const float*)d_in[5];
    const float* b_hh  = (const float*)d_in[6];
    const float* w_ans = (const float*)d_in[7];
    const float* b_ans = (const float*)d_in[8];
    const float* h0    = (const float*)d_in[9];
    const float* c0    = (const float*)d_in[10];

    // ---- MFMA-path ws layout (bytes) ----
    char* W = (char*)d_ws;
    float*    cT_m  = (float*)   (W);              // 262,144 B
    float*    poutm = (float*)   (W + 262144);     // 4,063,232 B
    ushort_t* xf_hi = (ushort_t*)(W + 4325376);    // 8,323,072 B
    ushort_t* xf_lo = (ushort_t*)(W + 12648448);   // 8,323,072 B
    ushort_t* hf_hi = (ushort_t*)(W + 20971520);   // 16,777,216 B
    ushort_t* hf_lo = (ushort_t*)(W + 37748736);   // 16,777,216 B
    int*      bar_m = (int*)     (W + 54525952);   // 2,048 B

    const int DYN_LDS = 96 * 1024 + 12288;         // A-frags + redA(8K) + redB(4K)

    hipError_t err = hipFuncSetAttribute(
        (const void*)lstm_mfma,
        hipFuncAttributeMaxDynamicSharedMemorySize, DYN_LDS);

    if (err == hipSuccess) {
        hipMemsetAsync(bar_m, 0, 2048, stream);
        init_mfma<<<256, 256, 0, stream>>>(h0, c0, cT_m, hf_hi, hf_lo);
        embed_frag<<<NSTEP, 256, 0, stream>>>(prob, embed, xf_hi, xf_lo);

        void* args[] = {
            (void*)&xf_hi, (void*)&xf_lo, (void*)&hf_hi, (void*)&hf_lo,
            (void*)&cT_m, (void*)&w_ih, (void*)&w_hh, (void*)&b_ih,
            (void*)&b_hh, (void*)&w_ans, (void*)&poutm, (void*)&bar_m
        };
        err = hipLaunchCooperativeKernel((const void*)lstm_mfma,
                                         dim3(256), dim3(1024),
                                         args, DYN_LDS, stream);
        if (err == hipSuccess) {
            finalize_mfma<<<NOUT, 256, 0, stream>>>(poutm, b_ans, (float*)d_out);
            return;
        }
    }

    // ---- fallback: round-9 proven path (aliases the same ws region) ----
    float* ws     = (float*)d_ws;
    float* cT     = ws;                    // 65,536 fl
    float* pout   = ws + 65536;            // 2,031,616 fl
    float* xT     = ws + 2097152;          // 4,161,536 fl
    float* h_hist = ws + 6258688;          // 8,388,608 fl
    int*   bar    = (int*)(ws + 14647296);

    hipMemsetAsync(bar, 0, 2048, stream);
    init_state<<<256, 256, 0, stream>>>(h0, c0, h_hist, cT);
    embed_transpose<<<NSTEP, 256, 0, stream>>>(prob, embed, xT);

    void* args9[] = {
        (void*)&xT, (void*)&h_hist, (void*)&cT,
        (void*)&w_ih, (void*)&w_hh, (void*)&b_ih, (void*)&b_hh,
        (void*)&w_ans, (void*)&pout, (void*)&bar
    };
    hipLaunchCooperativeKernel((const void*)lstm_persist_hist,
                               dim3(NBLK), dim3(NTHR), args9, 0, stream);
    finalize_persist<<<NOUT, 256, 0, stream>>>(pout, b_ans, (float*)d_out);
}